// Round 2
// baseline (299.009 us; speedup 1.0000x reference)
//
#include <hip/hip_runtime.h>
#include <hip/hip_bf16.h>
#include <math.h>

#define NN 50000
#define NE 800000
#define DIM 128
#define NH 4
#define HD 32
#define EH (NE * NH)          // 3,200,000
#define ATTN_SCALE 0.17677669529663687f   // 1/sqrt(32)
#define MTILE 64
#define GEMM_BLOCKS 782       // ceil(50000/64)
#define NBKT 98               // buckets of 512 nodes: dst>>9
#define PTS 2048              // edges per partition block
#define PBLKS 391             // ceil(NE/PTS)
#define HBLKS 104             // hist blocks: shallow atomic chains

typedef unsigned int uint;
typedef unsigned short ushort;
typedef __attribute__((ext_vector_type(8))) short short8;   // 8 bf16 (4 VGPRs)
typedef __attribute__((ext_vector_type(4))) float f32x4;    // MFMA acc

__device__ inline ushort f2bf(float f) {
    __hip_bfloat16 h = __float2bfloat16(f);   // round-to-nearest
    return *(ushort*)&h;
}
__device__ inline float bflo(uint u) { return __uint_as_float(u << 16); }
__device__ inline float bfhi(uint u) { return __uint_as_float(u & 0xffff0000u); }

// ---------------------------------------------------------------- prep
__global__ __launch_bounds__(256) void prep_x_kernel(
    const float* __restrict__ x, ushort* __restrict__ xb)
{
    const int i = blockIdx.x * 256 + threadIdx.x;     // one per 4 elems
    const float4 v = ((const float4*)x)[i];
    ushort4 o;
    o.x = f2bf(v.x); o.y = f2bf(v.y); o.z = f2bf(v.z); o.w = f2bf(v.w);
    ((ushort4*)xb)[i] = o;
}

// Wx = Wo @ Wm2  (Wm2 = rows 128..255 of Wm), fp32.
__global__ __launch_bounds__(128) void prep_wx_kernel(
    const float* __restrict__ Wo, const float* __restrict__ Wm,
    float* __restrict__ Wx)
{
    const int r = blockIdx.x, j = threadIdx.x;
    float acc = 0.f;
    for (int t = 0; t < 128; ++t)
        acc = fmaf(Wo[r * 128 + t], Wm[(128 + t) * 128 + j], acc);
    Wx[r * 128 + j] = acc;
}

// b' = bo @ Wm2 + bm.
__global__ __launch_bounds__(128) void prep_bias_kernel(
    const float* __restrict__ bo, const float* __restrict__ bm,
    const float* __restrict__ Wm, float* __restrict__ bprime)
{
    const int j = threadIdx.x;
    float acc = bm[j];
    for (int t = 0; t < 128; ++t)
        acc = fmaf(bo[t], Wm[(128 + t) * 128 + j], acc);
    bprime[j] = acc;
}

// Pack B operands into MFMA fragment order.
__global__ __launch_bounds__(256) void pack_qkv_kernel(
    const float* __restrict__ Wq, const float* __restrict__ Wk,
    const float* __restrict__ Wv, short* __restrict__ Bp)
{
    const int idx = blockIdx.x * 256 + threadIdx.x;   // 4*24*64*8 = 49152
    const int j = idx & 7, lane = (idx >> 3) & 63;
    const int rest = idx >> 9;                        // kc*24 + nt
    const int nt = rest % 24, kc = rest / 24;
    const int k = kc * 32 + (lane >> 4) * 8 + j;
    const int n = nt * 16 + (lane & 15);
    const float* W = (n < 128) ? Wq : (n < 256 ? Wk : Wv);
    Bp[idx] = (short)f2bf(W[k * 128 + (n & 127)]);
}

__global__ __launch_bounds__(256) void pack_out_kernel(
    const float* __restrict__ Wm, const float* __restrict__ Wx,
    short* __restrict__ Bp)
{
    const int idx = blockIdx.x * 256 + threadIdx.x;   // 8*8*64*8 = 32768
    const int j = idx & 7, lane = (idx >> 3) & 63;
    const int rest = idx >> 9;                        // kc*8 + nt
    const int nt = rest & 7, kc = rest >> 3;
    const int k = kc * 32 + (lane >> 4) * 8 + j;
    const int n = nt * 16 + (lane & 15);
    const float v = (k < 128) ? Wm[k * 128 + n] : Wx[(k - 128) * 128 + n];
    Bp[idx] = (short)f2bf(v);
}

// ------------------------------------------------- CSR build (bucketed)
__global__ __launch_bounds__(128) void bkt_zero_kernel(int* __restrict__ bkt_cnt)
{
    if (threadIdx.x < 128) bkt_cnt[threadIdx.x] = 0;
}

// grid-stride: few blocks -> shallow same-address atomic chains on flush
__global__ __launch_bounds__(256) void bkt_hist_kernel(
    const int* __restrict__ dst, int* __restrict__ bkt_cnt)
{
    __shared__ int c[NBKT];
    const int tid = threadIdx.x;
    if (tid < NBKT) c[tid] = 0;
    __syncthreads();
    for (int e = blockIdx.x * 256 + tid; e < NE; e += HBLKS * 256)
        atomicAdd(&c[dst[e] >> 9], 1);
    __syncthreads();
    if (tid < NBKT && c[tid]) atomicAdd(&bkt_cnt[tid], c[tid]);
}

__global__ void bkt_scan_kernel(const int* __restrict__ bkt_cnt,
                                int* __restrict__ bkt_base,
                                int* __restrict__ bkt_cursor,
                                int* __restrict__ rowptr)
{
    if (threadIdx.x == 0) {
        int run = 0;
        for (int b = 0; b < NBKT; ++b) {
            bkt_base[b] = run;
            bkt_cursor[b] = run;
            run += bkt_cnt[b];
        }
        bkt_base[NBKT] = run;   // == NE
        rowptr[NN] = run;
    }
}

// Phase 1: sequential read of edges, partition (with payload) into bucket
// regions. Per-bucket runs reserved with one global atomic per block.
__global__ __launch_bounds__(256) void partition_kernel(
    const int* __restrict__ src, const int* __restrict__ dst,
    const float* __restrict__ edge_attr, const float* __restrict__ We,
    int* __restrict__ bkt_cursor,
    int* __restrict__ psrc, int* __restrict__ pdst, float* __restrict__ peb)
{
    __shared__ int cnt[NBKT], rbase[NBKT], cnt2[NBKT];
    const int tid = threadIdx.x;
    if (tid < NBKT) cnt[tid] = 0;
    __syncthreads();
    const int e0 = blockIdx.x * PTS;
    #pragma unroll
    for (int it = 0; it < 8; ++it) {
        const int e = e0 + it * 256 + tid;
        if (e < NE) atomicAdd(&cnt[dst[e] >> 9], 1);
    }
    __syncthreads();
    if (tid < NBKT) {
        rbase[tid] = cnt[tid] ? atomicAdd(&bkt_cursor[tid], cnt[tid]) : 0;
        cnt2[tid] = 0;
    }
    __syncthreads();
    #pragma unroll
    for (int it = 0; it < 8; ++it) {
        const int e = e0 + it * 256 + tid;
        if (e < NE) {
            const int d = dst[e];
            const int b = d >> 9;
            const int r = atomicAdd(&cnt2[b], 1);
            const int pos = rbase[b] + r;
            psrc[pos] = src[e];
            pdst[pos] = d;
            const float a0 = edge_attr[e * 3 + 0];
            const float a1 = edge_attr[e * 3 + 1];
            const float a2 = edge_attr[e * 3 + 2];
            float4 eb;
            eb.x = a0 * We[0] + a1 * We[4] + a2 * We[8];
            eb.y = a0 * We[1] + a1 * We[5] + a2 * We[9];
            eb.z = a0 * We[2] + a1 * We[6] + a2 * We[10];
            eb.w = a0 * We[3] + a1 * We[7] + a2 * We[11];
            *(float4*)(peb + (size_t)pos * 4) = eb;
        }
    }
}

// Phase 2: one block per bucket. Per-node hist + scan in LDS; write rowptr;
// scatter payload (src + edge bias only — dst is implicit downstream).
__global__ __launch_bounds__(256) void bucket_csr_kernel(
    const int* __restrict__ bkt_base,
    const int* __restrict__ psrc, const int* __restrict__ pdst,
    const float* __restrict__ peb,
    int* __restrict__ rowptr,
    int* __restrict__ srcp, float* __restrict__ eb_csr)
{
    __shared__ int cnt[512];
    __shared__ int pre[512];
    __shared__ int sc[256];
    const int tid = threadIdx.x;
    const int b = blockIdx.x;
    const int base = bkt_base[b];
    const int n = bkt_base[b + 1] - base;
    const int node0 = b << 9;

    cnt[tid] = 0; cnt[tid + 256] = 0;
    __syncthreads();
    for (int i = base + tid; i < base + n; i += 256)
        atomicAdd(&cnt[pdst[i] - node0], 1);
    __syncthreads();

    // exclusive scan of 512 counters: pair-sum -> 256-scan -> expand
    const int pair = cnt[2 * tid] + cnt[2 * tid + 1];
    sc[tid] = pair;
    __syncthreads();
    for (int off = 1; off < 256; off <<= 1) {
        const int v = (tid >= off) ? sc[tid - off] : 0;
        __syncthreads();
        sc[tid] += v;
        __syncthreads();
    }
    const int ex = sc[tid] - pair;
    pre[2 * tid] = base + ex;
    pre[2 * tid + 1] = base + ex + cnt[2 * tid];
    __syncthreads();

    // rowptr (before pre is consumed as cursor)
    for (int l = tid; l < 512; l += 256) {
        const int g = node0 + l;
        if (g < NN) rowptr[g] = pre[l];
    }
    __syncthreads();

    for (int i = base + tid; i < base + n; i += 256) {
        const int d = pdst[i];
        const int pos = atomicAdd(&pre[d - node0], 1);
        srcp[pos] = psrc[i];
        *(float4*)(eb_csr + (size_t)pos * 4) =
            *(const float4*)(peb + (size_t)i * 4);
    }
}

// ---------------------------------------------------------------- QKV MFMA
__global__ __launch_bounds__(256) void qkv_mfma_kernel(
    const ushort* __restrict__ xb, const short* __restrict__ Bp,
    ushort* __restrict__ Qb, ushort* __restrict__ Kb, ushort* __restrict__ Vb)
{
    const int wave = threadIdx.x >> 6;
    const int lane = threadIdx.x & 63;
    const int m = lane & 15, quad = lane >> 4;
    const int row0w = blockIdx.x * MTILE + wave * 16;
    const int arow = row0w + m;
    const bool rowok = arow < NN;

    short8 a[4];
    #pragma unroll
    for (int kc = 0; kc < 4; ++kc)
        a[kc] = rowok ? *(const short8*)(xb + (size_t)arow * 128 + kc * 32 + quad * 8)
                      : (short8)(0);

    const int NT = 24;
    for (int nt = 0; nt < NT; nt += 2) {
        f32x4 acc0 = {0.f, 0.f, 0.f, 0.f}, acc1 = {0.f, 0.f, 0.f, 0.f};
        #pragma unroll
        for (int kc = 0; kc < 4; ++kc) {
            const short8 b0 = *(const short8*)(Bp + ((size_t)(kc * NT + nt) * 64 + lane) * 8);
            const short8 b1 = *(const short8*)(Bp + ((size_t)(kc * NT + nt + 1) * 64 + lane) * 8);
            acc0 = __builtin_amdgcn_mfma_f32_16x16x32_bf16(a[kc], b0, acc0, 0, 0, 0);
            acc1 = __builtin_amdgcn_mfma_f32_16x16x32_bf16(a[kc], b1, acc1, 0, 0, 0);
        }
        #pragma unroll
        for (int t = 0; t < 2; ++t) {
            const f32x4 acc = t ? acc1 : acc0;
            const int c = (nt + t) * 16 + m;           // global col in [0,384)
            ushort* dstp_ = (c < 128) ? Qb : (c < 256 ? Kb : Vb);
            const int lc = c & 127;
            #pragma unroll
            for (int g = 0; g < 4; ++g) {
                const int r = row0w + quad * 4 + g;
                if (r < NN) dstp_[(size_t)r * 128 + lc] = f2bf(acc[g]);
            }
        }
    }
}

// ---------------------------------------------------------------- OUT MFMA
__global__ __launch_bounds__(256) void out_mfma_kernel(
    const ushort* __restrict__ xb, const ushort* __restrict__ aggb,
    const short* __restrict__ Bp, const float* __restrict__ bprime,
    float* __restrict__ out)
{
    const int wave = threadIdx.x >> 6;
    const int lane = threadIdx.x & 63;
    const int m = lane & 15, quad = lane >> 4;
    const int row0w = blockIdx.x * MTILE + wave * 16;
    const int arow = row0w + m;
    const bool rowok = arow < NN;

    short8 a[8];
    #pragma unroll
    for (int kc = 0; kc < 4; ++kc)
        a[kc] = rowok ? *(const short8*)(xb + (size_t)arow * 128 + kc * 32 + quad * 8)
                      : (short8)(0);
    #pragma unroll
    for (int kc = 0; kc < 4; ++kc)
        a[4 + kc] = rowok ? *(const short8*)(aggb + (size_t)arow * 128 + kc * 32 + quad * 8)
                          : (short8)(0);

    const int NT = 8;
    for (int nt = 0; nt < NT; nt += 2) {
        f32x4 acc0 = {0.f, 0.f, 0.f, 0.f}, acc1 = {0.f, 0.f, 0.f, 0.f};
        #pragma unroll
        for (int kc = 0; kc < 8; ++kc) {
            const short8 b0 = *(const short8*)(Bp + ((size_t)(kc * NT + nt) * 64 + lane) * 8);
            const short8 b1 = *(const short8*)(Bp + ((size_t)(kc * NT + nt + 1) * 64 + lane) * 8);
            acc0 = __builtin_amdgcn_mfma_f32_16x16x32_bf16(a[kc], b0, acc0, 0, 0, 0);
            acc1 = __builtin_amdgcn_mfma_f32_16x16x32_bf16(a[kc], b1, acc1, 0, 0, 0);
        }
        #pragma unroll
        for (int t = 0; t < 2; ++t) {
            const f32x4 acc = t ? acc1 : acc0;
            const int c = (nt + t) * 16 + m;           // global col in [0,128)
            const float bb = bprime[c];
            #pragma unroll
            for (int g = 0; g < 4; ++g) {
                const int r = row0w + quad * 4 + g;
                if (r < NN) out[(size_t)r * 128 + c] = fmaxf(acc[g] + bb, 0.f);
            }
        }
    }
}

// ----------------------------------------- FUSED attn + softmax + aggregate
// One wave per node; 4 groups of 16 lanes, each group owns one edge of a
// 4-edge "quad". Lane layout: g = lane>>4 (edge slot), t = lane&15 (8-dim
// dwordx4 chunk), h = t>>2 (head of chunk).
//
// 3-deep software pipeline (latency-bound fix, round 2):
//   compute quad A | K/V of quads B and C in flight | indices of quad D
//   prefetching. All indices clamped to end-1 and weights masked -> the
//   loop body is branch-free; phantom loads past the row end hit the
//   just-used cache line (no extra HBM).
__global__ __launch_bounds__(256) void attn_agg_kernel(
    const ushort* __restrict__ Qb, const ushort* __restrict__ Kb,
    const ushort* __restrict__ Vb,
    const int* __restrict__ rowptr, const int* __restrict__ srcp,
    const float* __restrict__ eb_csr, ushort* __restrict__ aggb)
{
    const int tid = threadIdx.x;
    const int d = blockIdx.x * 4 + (tid >> 6);
    const int lane = tid & 63;
    const int g = lane >> 4;          // edge slot within quad
    const int t = lane & 15;          // 8-dim chunk index
    const int h = t >> 2;             // head of this chunk
    const int begin = rowptr[d];
    const int end   = rowptr[d + 1];

    // Q chunk, unpacked once.
    const uint4 uq = *(const uint4*)(Qb + (size_t)d * DIM + 8 * t);
    float q0 = bflo(uq.x), q1 = bfhi(uq.x);
    float q2 = bflo(uq.y), q3 = bfhi(uq.y);
    float q4 = bflo(uq.z), q5 = bfhi(uq.z);
    float q6 = bflo(uq.w), q7 = bfhi(uq.w);

    float ss = 0.f;
    float a0 = 0.f, a1 = 0.f, a2 = 0.f, a3 = 0.f;
    float a4 = 0.f, a5 = 0.f, a6 = 0.f, a7 = 0.f;

    if (begin < end) {
        const int last = end - 1;
        const ushort* kbase = Kb + 8 * t;
        const ushort* vbase = Vb + 8 * t;

        // ---- prologue: indices for quads 0,1,2; values for quads 0,1
        int e0 = begin + g;      e0 = (e0 > last) ? last : e0;
        int e1 = begin + 4 + g;  e1 = (e1 > last) ? last : e1;
        int e2 = begin + 8 + g;  e2 = (e2 > last) ? last : e2;
        int   sA = srcp[e0];  float ebA = eb_csr[(size_t)e0 * 4 + h];
        int   sB = srcp[e1];  float ebB = eb_csr[(size_t)e1 * 4 + h];
        int   sC = srcp[e2];  float ebC = eb_csr[(size_t)e2 * 4 + h];
        uint4 ukA = *(const uint4*)(kbase + (size_t)sA * DIM);
        uint4 uvA = *(const uint4*)(vbase + (size_t)sA * DIM);
        uint4 ukB = *(const uint4*)(kbase + (size_t)sB * DIM);
        uint4 uvB = *(const uint4*)(vbase + (size_t)sB * DIM);

        for (int p = begin; p < end; p += 4) {
            // issue quad-C values (indices already resident)
            const uint4 ukC = *(const uint4*)(kbase + (size_t)sC * DIM);
            const uint4 uvC = *(const uint4*)(vbase + (size_t)sC * DIM);
            // prefetch quad-D indices
            int e3 = p + 12 + g; e3 = (e3 > last) ? last : e3;
            const int   sD  = srcp[e3];
            const float ebD = eb_csr[(size_t)e3 * 4 + h];

            // ---- compute quad A
            const bool ok = (p + g) < end;
            float da = q0 * bflo(ukA.x);
            float db = q1 * bfhi(ukA.x);
            da = fmaf(q2, bflo(ukA.y), da);
            db = fmaf(q3, bfhi(ukA.y), db);
            da = fmaf(q4, bflo(ukA.z), da);
            db = fmaf(q5, bfhi(ukA.z), db);
            da = fmaf(q6, bflo(ukA.w), da);
            db = fmaf(q7, bfhi(ukA.w), db);
            float part = da + db;
            part += __shfl_xor(part, 1);
            part += __shfl_xor(part, 2);   // lanes h*4..h*4+3 hold head-dot

            float a = fmaf(part, ATTN_SCALE, ebA);
            a = (a >= 0.f) ? a : 0.2f * a;
            const float w = ok ? __expf(a) : 0.f;

            ss += w;
            a0 = fmaf(w, bflo(uvA.x), a0);
            a1 = fmaf(w, bfhi(uvA.x), a1);
            a2 = fmaf(w, bflo(uvA.y), a2);
            a3 = fmaf(w, bfhi(uvA.y), a3);
            a4 = fmaf(w, bflo(uvA.z), a4);
            a5 = fmaf(w, bfhi(uvA.z), a5);
            a6 = fmaf(w, bflo(uvA.w), a6);
            a7 = fmaf(w, bfhi(uvA.w), a7);

            // ---- rotate pipeline
            ukA = ukB; uvA = uvB; ebA = ebB;
            ukB = ukC; uvB = uvC; ebB = ebC;
            sC = sD;   ebC = ebD;
        }
    }

    // cross-group reduction (once per node): 4 edge slots -> totals
    ss += __shfl_xor(ss, 16);
    ss += __shfl_xor(ss, 32);
    a0 += __shfl_xor(a0, 16); a0 += __shfl_xor(a0, 32);
    a1 += __shfl_xor(a1, 16); a1 += __shfl_xor(a1, 32);
    a2 += __shfl_xor(a2, 16); a2 += __shfl_xor(a2, 32);
    a3 += __shfl_xor(a3, 16); a3 += __shfl_xor(a3, 32);
    a4 += __shfl_xor(a4, 16); a4 += __shfl_xor(a4, 32);
    a5 += __shfl_xor(a5, 16); a5 += __shfl_xor(a5, 32);
    a6 += __shfl_xor(a6, 16); a6 += __shfl_xor(a6, 32);
    a7 += __shfl_xor(a7, 16); a7 += __shfl_xor(a7, 32);

    if (g == 0) {
        const float inv = 1.f / fmaxf(ss, 1e-12f);
        uint4 o;
        o.x = (uint)f2bf(a0 * inv) | ((uint)f2bf(a1 * inv) << 16);
        o.y = (uint)f2bf(a2 * inv) | ((uint)f2bf(a3 * inv) << 16);
        o.z = (uint)f2bf(a4 * inv) | ((uint)f2bf(a5 * inv) << 16);
        o.w = (uint)f2bf(a6 * inv) | ((uint)f2bf(a7 * inv) << 16);
        *(uint4*)(aggb + (size_t)d * DIM + 8 * t) = o;
    }
}

// ----------------------------------------------------------------- launch
extern "C" void kernel_launch(void* const* d_in, const int* in_sizes, int n_in,
                              void* d_out, int out_size, void* d_ws, size_t ws_size,
                              hipStream_t stream)
{
    const float* x         = (const float*)d_in[0];
    const int*   edge_idx  = (const int*)d_in[1];   // [2,E]: row0=src, row1=dst
    const float* edge_attr = (const float*)d_in[2];
    const float* Wq        = (const float*)d_in[3];
    const float* Wk        = (const float*)d_in[4];
    const float* Wv        = (const float*)d_in[5];
    const float* We        = (const float*)d_in[6];
    const float* Wo        = (const float*)d_in[7];
    const float* bo        = (const float*)d_in[8];
    const float* Wm        = (const float*)d_in[9];
    const float* bm        = (const float*)d_in[10];
    float* out = (float*)d_out;

    const int* src = edge_idx;
    const int* dst = edge_idx + NE;

    // workspace layout
    ushort* xb   = (ushort*)d_ws;                 // 6,400,000 us
    ushort* Qb   = xb + (size_t)NN * DIM;         // 6,400,000 us
    ushort* Kb   = Qb + (size_t)NN * DIM;         // 6,400,000 us
    ushort* Vb   = Kb + (size_t)NN * DIM;         // 6,400,000 us
    ushort* aggb = Vb + (size_t)NN * DIM;         // 6,400,000 us
    int*   psrc     = (int*)(aggb + (size_t)NN * DIM);  // 800,000 i
    int*   pdst     = psrc + NE;                  // 800,000 i
    float* peb      = (float*)(pdst + NE);        // 3,200,000 f
    float* eb_csr   = peb + (size_t)EH;           // 3,200,000 f
    float* Wx       = eb_csr + (size_t)EH;        // 16,384 f
    float* bprime   = Wx + 16384;                 // 128 f
    short* BpQKV    = (short*)(bprime + 128);     // 49,152 s
    short* BpOut    = BpQKV + 49152;              // 32,768 s
    int*   rowptr   = (int*)(BpOut + 32768);      // 50,048 i (50001 used)
    int*   srcp     = rowptr + 50048;             // 800,000 i
    int*   bkt_cnt    = srcp + NE;                // 128 i
    int*   bkt_base   = bkt_cnt + 128;            // 128 i (NBKT+1 used)
    int*   bkt_cursor = bkt_base + 128;           // 128 i

    // prep: bf16 x, fused epilogue weights, packed B operands
    prep_x_kernel<<<(NN * DIM / 4) / 256, 256, 0, stream>>>(x, xb);
    prep_wx_kernel<<<128, 128, 0, stream>>>(Wo, Wm, Wx);
    prep_bias_kernel<<<1, 128, 0, stream>>>(bo, bm, Wm, bprime);
    pack_qkv_kernel<<<192, 256, 0, stream>>>(Wq, Wk, Wv, BpQKV);
    pack_out_kernel<<<128, 256, 0, stream>>>(Wm, Wx, BpOut);

    // CSR build — bucketed two-phase sort, no global random scatter
    bkt_zero_kernel<<<1, 128, 0, stream>>>(bkt_cnt);
    bkt_hist_kernel<<<HBLKS, 256, 0, stream>>>(dst, bkt_cnt);
    bkt_scan_kernel<<<1, 64, 0, stream>>>(bkt_cnt, bkt_base, bkt_cursor, rowptr);
    partition_kernel<<<PBLKS, 256, 0, stream>>>(src, dst, edge_attr, We,
                                                bkt_cursor, psrc, pdst, peb);
    bucket_csr_kernel<<<NBKT, 256, 0, stream>>>(bkt_base, psrc, pdst, peb,
                                                rowptr, srcp, eb_csr);

    // main pipeline
    qkv_mfma_kernel<<<GEMM_BLOCKS, 256, 0, stream>>>(xb, BpQKV, Qb, Kb, Vb);
    attn_agg_kernel<<<NN / 4, 256, 0, stream>>>(Qb, Kb, Vb, rowptr, srcp,
                                                eb_csr, aggb);
    out_mfma_kernel<<<GEMM_BLOCKS, 256, 0, stream>>>(xb, aggb, BpOut, bprime, out);
}

// Round 3
// 278.557 us; speedup vs baseline: 1.0734x; 1.0734x over previous
//
#include <hip/hip_runtime.h>
#include <hip/hip_bf16.h>
#include <math.h>

#define NN 50000
#define NE 800000
#define DIM 128
#define NH 4
#define HD 32
#define EH (NE * NH)          // 3,200,000
#define ATTN_SCALE 0.17677669529663687f   // 1/sqrt(32)
#define MTILE 64
#define GEMM_BLOCKS 782       // ceil(50000/64)
#define NBKT 98               // buckets of 512 nodes: dst>>9
#define PTS 2048              // edges per partition block
#define PBLKS 391             // ceil(NE/PTS)
#define HBLKS 104             // hist blocks: shallow atomic chains

typedef unsigned int uint;
typedef unsigned short ushort;
typedef __attribute__((ext_vector_type(8))) short short8;   // 8 bf16 (4 VGPRs)
typedef __attribute__((ext_vector_type(4))) float f32x4;    // MFMA acc

__device__ inline ushort f2bf(float f) {
    __hip_bfloat16 h = __float2bfloat16(f);   // round-to-nearest
    return *(ushort*)&h;
}
__device__ inline float bflo(uint u) { return __uint_as_float(u << 16); }
__device__ inline float bfhi(uint u) { return __uint_as_float(u & 0xffff0000u); }

// ---------------------------------------------------------------- prep
// Also zeroes bkt_cnt (folded bkt_zero launch; stream-ordered before hist).
__global__ __launch_bounds__(256) void prep_x_kernel(
    const float* __restrict__ x, ushort* __restrict__ xb,
    int* __restrict__ bkt_cnt)
{
    if (blockIdx.x == 0 && threadIdx.x < 128) bkt_cnt[threadIdx.x] = 0;
    const int i = blockIdx.x * 256 + threadIdx.x;     // one per 4 elems
    const float4 v = ((const float4*)x)[i];
    ushort4 o;
    o.x = f2bf(v.x); o.y = f2bf(v.y); o.z = f2bf(v.z); o.w = f2bf(v.w);
    ((ushort4*)xb)[i] = o;
}

// Wx = Wo @ Wm2 (Wm2 = rows 128..255 of Wm), fp32; block 128 does b'.
__global__ __launch_bounds__(128) void prep_wxb_kernel(
    const float* __restrict__ Wo, const float* __restrict__ Wm,
    const float* __restrict__ bo, const float* __restrict__ bm,
    float* __restrict__ Wx, float* __restrict__ bprime)
{
    const int r = blockIdx.x, j = threadIdx.x;
    if (r < 128) {
        float acc = 0.f;
        for (int t = 0; t < 128; ++t)
            acc = fmaf(Wo[r * 128 + t], Wm[(128 + t) * 128 + j], acc);
        Wx[r * 128 + j] = acc;
    } else {
        float acc = bm[j];
        for (int t = 0; t < 128; ++t)
            acc = fmaf(bo[t], Wm[(128 + t) * 128 + j], acc);
        bprime[j] = acc;
    }
}

// Pack B operands into MFMA fragment order.
__global__ __launch_bounds__(256) void pack_qkv_kernel(
    const float* __restrict__ Wq, const float* __restrict__ Wk,
    const float* __restrict__ Wv, short* __restrict__ Bp)
{
    const int idx = blockIdx.x * 256 + threadIdx.x;   // 4*24*64*8 = 49152
    const int j = idx & 7, lane = (idx >> 3) & 63;
    const int rest = idx >> 9;                        // kc*24 + nt
    const int nt = rest % 24, kc = rest / 24;
    const int k = kc * 32 + (lane >> 4) * 8 + j;
    const int n = nt * 16 + (lane & 15);
    const float* W = (n < 128) ? Wq : (n < 256 ? Wk : Wv);
    Bp[idx] = (short)f2bf(W[k * 128 + (n & 127)]);
}

__global__ __launch_bounds__(256) void pack_out_kernel(
    const float* __restrict__ Wm, const float* __restrict__ Wx,
    short* __restrict__ Bp)
{
    const int idx = blockIdx.x * 256 + threadIdx.x;   // 8*8*64*8 = 32768
    const int j = idx & 7, lane = (idx >> 3) & 63;
    const int rest = idx >> 9;                        // kc*8 + nt
    const int nt = rest & 7, kc = rest >> 3;
    const int k = kc * 32 + (lane >> 4) * 8 + j;
    const int n = nt * 16 + (lane & 15);
    const float v = (k < 128) ? Wm[k * 128 + n] : Wx[(k - 128) * 128 + n];
    Bp[idx] = (short)f2bf(v);
}

// ------------------------------------------------- CSR build (bucketed)
// grid-stride: few blocks -> shallow same-address atomic chains on flush
__global__ __launch_bounds__(256) void bkt_hist_kernel(
    const int* __restrict__ dst, int* __restrict__ bkt_cnt)
{
    __shared__ int c[NBKT];
    const int tid = threadIdx.x;
    if (tid < NBKT) c[tid] = 0;
    __syncthreads();
    for (int e = blockIdx.x * 256 + tid; e < NE; e += HBLKS * 256)
        atomicAdd(&c[dst[e] >> 9], 1);
    __syncthreads();
    if (tid < NBKT && c[tid]) atomicAdd(&bkt_cnt[tid], c[tid]);
}

__global__ void bkt_scan_kernel(const int* __restrict__ bkt_cnt,
                                int* __restrict__ bkt_base,
                                int* __restrict__ bkt_cursor,
                                int* __restrict__ rowptr)
{
    if (threadIdx.x == 0) {
        int run = 0;
        for (int b = 0; b < NBKT; ++b) {
            bkt_base[b] = run;
            bkt_cursor[b] = run;
            run += bkt_cnt[b];
        }
        bkt_base[NBKT] = run;   // == NE
        rowptr[NN] = run;
    }
}

// Phase 1: sequential read of edges, partition (with payload) into bucket
// regions. Per-bucket runs reserved with one global atomic per block.
__global__ __launch_bounds__(256) void partition_kernel(
    const int* __restrict__ src, const int* __restrict__ dst,
    const float* __restrict__ edge_attr, const float* __restrict__ We,
    int* __restrict__ bkt_cursor,
    int* __restrict__ psrc, int* __restrict__ pdst, float* __restrict__ peb)
{
    __shared__ int cnt[NBKT], rbase[NBKT], cnt2[NBKT];
    const int tid = threadIdx.x;
    if (tid < NBKT) cnt[tid] = 0;
    __syncthreads();
    const int e0 = blockIdx.x * PTS;
    #pragma unroll
    for (int it = 0; it < 8; ++it) {
        const int e = e0 + it * 256 + tid;
        if (e < NE) atomicAdd(&cnt[dst[e] >> 9], 1);
    }
    __syncthreads();
    if (tid < NBKT) {
        rbase[tid] = cnt[tid] ? atomicAdd(&bkt_cursor[tid], cnt[tid]) : 0;
        cnt2[tid] = 0;
    }
    __syncthreads();
    #pragma unroll
    for (int it = 0; it < 8; ++it) {
        const int e = e0 + it * 256 + tid;
        if (e < NE) {
            const int d = dst[e];
            const int b = d >> 9;
            const int r = atomicAdd(&cnt2[b], 1);
            const int pos = rbase[b] + r;
            psrc[pos] = src[e];
            pdst[pos] = d;
            const float a0 = edge_attr[e * 3 + 0];
            const float a1 = edge_attr[e * 3 + 1];
            const float a2 = edge_attr[e * 3 + 2];
            float4 eb;
            eb.x = a0 * We[0] + a1 * We[4] + a2 * We[8];
            eb.y = a0 * We[1] + a1 * We[5] + a2 * We[9];
            eb.z = a0 * We[2] + a1 * We[6] + a2 * We[10];
            eb.w = a0 * We[3] + a1 * We[7] + a2 * We[11];
            *(float4*)(peb + (size_t)pos * 4) = eb;
        }
    }
}

// Phase 2: one block per bucket. Per-node hist + scan in LDS; write rowptr;
// scatter payload (src + edge bias only — dst is implicit downstream).
__global__ __launch_bounds__(256) void bucket_csr_kernel(
    const int* __restrict__ bkt_base,
    const int* __restrict__ psrc, const int* __restrict__ pdst,
    const float* __restrict__ peb,
    int* __restrict__ rowptr,
    int* __restrict__ srcp, float* __restrict__ eb_csr)
{
    __shared__ int cnt[512];
    __shared__ int pre[512];
    __shared__ int sc[256];
    const int tid = threadIdx.x;
    const int b = blockIdx.x;
    const int base = bkt_base[b];
    const int n = bkt_base[b + 1] - base;
    const int node0 = b << 9;

    cnt[tid] = 0; cnt[tid + 256] = 0;
    __syncthreads();
    for (int i = base + tid; i < base + n; i += 256)
        atomicAdd(&cnt[pdst[i] - node0], 1);
    __syncthreads();

    // exclusive scan of 512 counters: pair-sum -> 256-scan -> expand
    const int pair = cnt[2 * tid] + cnt[2 * tid + 1];
    sc[tid] = pair;
    __syncthreads();
    for (int off = 1; off < 256; off <<= 1) {
        const int v = (tid >= off) ? sc[tid - off] : 0;
        __syncthreads();
        sc[tid] += v;
        __syncthreads();
    }
    const int ex = sc[tid] - pair;
    pre[2 * tid] = base + ex;
    pre[2 * tid + 1] = base + ex + cnt[2 * tid];
    __syncthreads();

    // rowptr (before pre is consumed as cursor)
    for (int l = tid; l < 512; l += 256) {
        const int g = node0 + l;
        if (g < NN) rowptr[g] = pre[l];
    }
    __syncthreads();

    for (int i = base + tid; i < base + n; i += 256) {
        const int d = pdst[i];
        const int pos = atomicAdd(&pre[d - node0], 1);
        srcp[pos] = psrc[i];
        *(float4*)(eb_csr + (size_t)pos * 4) =
            *(const float4*)(peb + (size_t)i * 4);
    }
}

// ---------------------------------------------------------------- QKV MFMA
__global__ __launch_bounds__(256) void qkv_mfma_kernel(
    const ushort* __restrict__ xb, const short* __restrict__ Bp,
    ushort* __restrict__ Qb, ushort* __restrict__ Kb, ushort* __restrict__ Vb)
{
    const int wave = threadIdx.x >> 6;
    const int lane = threadIdx.x & 63;
    const int m = lane & 15, quad = lane >> 4;
    const int row0w = blockIdx.x * MTILE + wave * 16;
    const int arow = row0w + m;
    const bool rowok = arow < NN;

    short8 a[4];
    #pragma unroll
    for (int kc = 0; kc < 4; ++kc)
        a[kc] = rowok ? *(const short8*)(xb + (size_t)arow * 128 + kc * 32 + quad * 8)
                      : (short8)(0);

    const int NT = 24;
    for (int nt = 0; nt < NT; nt += 2) {
        f32x4 acc0 = {0.f, 0.f, 0.f, 0.f}, acc1 = {0.f, 0.f, 0.f, 0.f};
        #pragma unroll
        for (int kc = 0; kc < 4; ++kc) {
            const short8 b0 = *(const short8*)(Bp + ((size_t)(kc * NT + nt) * 64 + lane) * 8);
            const short8 b1 = *(const short8*)(Bp + ((size_t)(kc * NT + nt + 1) * 64 + lane) * 8);
            acc0 = __builtin_amdgcn_mfma_f32_16x16x32_bf16(a[kc], b0, acc0, 0, 0, 0);
            acc1 = __builtin_amdgcn_mfma_f32_16x16x32_bf16(a[kc], b1, acc1, 0, 0, 0);
        }
        #pragma unroll
        for (int t = 0; t < 2; ++t) {
            const f32x4 acc = t ? acc1 : acc0;
            const int c = (nt + t) * 16 + m;           // global col in [0,384)
            ushort* dstp_ = (c < 128) ? Qb : (c < 256 ? Kb : Vb);
            const int lc = c & 127;
            #pragma unroll
            for (int g = 0; g < 4; ++g) {
                const int r = row0w + quad * 4 + g;
                if (r < NN) dstp_[(size_t)r * 128 + lc] = f2bf(acc[g]);
            }
        }
    }
}

// ---------------------------------------------------------------- OUT MFMA
__global__ __launch_bounds__(256) void out_mfma_kernel(
    const ushort* __restrict__ xb, const ushort* __restrict__ aggb,
    const short* __restrict__ Bp, const float* __restrict__ bprime,
    float* __restrict__ out)
{
    const int wave = threadIdx.x >> 6;
    const int lane = threadIdx.x & 63;
    const int m = lane & 15, quad = lane >> 4;
    const int row0w = blockIdx.x * MTILE + wave * 16;
    const int arow = row0w + m;
    const bool rowok = arow < NN;

    short8 a[8];
    #pragma unroll
    for (int kc = 0; kc < 4; ++kc)
        a[kc] = rowok ? *(const short8*)(xb + (size_t)arow * 128 + kc * 32 + quad * 8)
                      : (short8)(0);
    #pragma unroll
    for (int kc = 0; kc < 4; ++kc)
        a[4 + kc] = rowok ? *(const short8*)(aggb + (size_t)arow * 128 + kc * 32 + quad * 8)
                          : (short8)(0);

    const int NT = 8;
    for (int nt = 0; nt < NT; nt += 2) {
        f32x4 acc0 = {0.f, 0.f, 0.f, 0.f}, acc1 = {0.f, 0.f, 0.f, 0.f};
        #pragma unroll
        for (int kc = 0; kc < 8; ++kc) {
            const short8 b0 = *(const short8*)(Bp + ((size_t)(kc * NT + nt) * 64 + lane) * 8);
            const short8 b1 = *(const short8*)(Bp + ((size_t)(kc * NT + nt + 1) * 64 + lane) * 8);
            acc0 = __builtin_amdgcn_mfma_f32_16x16x32_bf16(a[kc], b0, acc0, 0, 0, 0);
            acc1 = __builtin_amdgcn_mfma_f32_16x16x32_bf16(a[kc], b1, acc1, 0, 0, 0);
        }
        #pragma unroll
        for (int t = 0; t < 2; ++t) {
            const f32x4 acc = t ? acc1 : acc0;
            const int c = (nt + t) * 16 + m;           // global col in [0,128)
            const float bb = bprime[c];
            #pragma unroll
            for (int g = 0; g < 4; ++g) {
                const int r = row0w + quad * 4 + g;
                if (r < NN) out[(size_t)r * 128 + c] = fmaxf(acc[g] + bb, 0.f);
            }
        }
    }
}

// ----------------------------------------- FUSED attn + softmax + aggregate
// One wave per node; 4 groups of 16 lanes. Per iteration the wave processes
// EIGHT edges as two structurally independent chains X (edges p..p+3) and
// Y (edges p+4..p+7) with separate source regs, bias regs, ok-masks and
// accumulator sets — not collapsible by copy-prop, so >=4 value-gathers
// stay in flight per wave (round-2's rotation pipeline was copy-propagated
// away: VGPR stayed 28). Indices for the next pair are prefetched. All
// indices clamped to end-1, weights masked -> branch-free body.
__global__ __launch_bounds__(256) void attn_agg_kernel(
    const ushort* __restrict__ Qb, const ushort* __restrict__ Kb,
    const ushort* __restrict__ Vb,
    const int* __restrict__ rowptr, const int* __restrict__ srcp,
    const float* __restrict__ eb_csr, ushort* __restrict__ aggb)
{
    const int tid = threadIdx.x;
    const int d = blockIdx.x * 4 + (tid >> 6);
    const int lane = tid & 63;
    const int g = lane >> 4;          // edge slot within quad
    const int t = lane & 15;          // 8-dim chunk index
    const int h = t >> 2;             // head of this chunk
    const int begin = rowptr[d];
    const int end   = rowptr[d + 1];

    // Q chunk, unpacked once.
    const uint4 uq = *(const uint4*)(Qb + (size_t)d * DIM + 8 * t);
    const float q0 = bflo(uq.x), q1 = bfhi(uq.x);
    const float q2 = bflo(uq.y), q3 = bfhi(uq.y);
    const float q4 = bflo(uq.z), q5 = bfhi(uq.z);
    const float q6 = bflo(uq.w), q7 = bfhi(uq.w);

    float ssX = 0.f, x0 = 0.f, x1 = 0.f, x2 = 0.f, x3 = 0.f;
    float               x4 = 0.f, x5 = 0.f, x6 = 0.f, x7 = 0.f;
    float ssY = 0.f, y0 = 0.f, y1 = 0.f, y2 = 0.f, y3 = 0.f;
    float               y4 = 0.f, y5 = 0.f, y6 = 0.f, y7 = 0.f;

    if (begin < end) {
        const int last = end - 1;
        const ushort* kbase = Kb + 8 * t;
        const ushort* vbase = Vb + 8 * t;

        int eX = begin + g;      eX = (eX > last) ? last : eX;
        int eY = begin + 4 + g;  eY = (eY > last) ? last : eY;
        int   sX  = srcp[eX];
        int   sY  = srcp[eY];
        float ebX = eb_csr[(size_t)eX * 4 + h];
        float ebY = eb_csr[(size_t)eY * 4 + h];

        for (int p = begin; p < end; p += 8) {
            // prefetch next pair's indices + biases
            int eXn = p + 8 + g;   eXn = (eXn > last) ? last : eXn;
            int eYn = p + 12 + g;  eYn = (eYn > last) ? last : eYn;
            const int   sXn  = srcp[eXn];
            const int   sYn  = srcp[eYn];
            const float ebXn = eb_csr[(size_t)eXn * 4 + h];
            const float ebYn = eb_csr[(size_t)eYn * 4 + h];

            // gathers for both chains — independent, cluster at top
            const uint4 ukX = *(const uint4*)(kbase + (size_t)sX * DIM);
            const uint4 uvX = *(const uint4*)(vbase + (size_t)sX * DIM);
            const uint4 ukY = *(const uint4*)(kbase + (size_t)sY * DIM);
            const uint4 uvY = *(const uint4*)(vbase + (size_t)sY * DIM);

            // ---- chain X (edges p..p+3)
            {
                const bool ok = (p + g) < end;
                float da = q0 * bflo(ukX.x);
                float db = q1 * bfhi(ukX.x);
                da = fmaf(q2, bflo(ukX.y), da);
                db = fmaf(q3, bfhi(ukX.y), db);
                da = fmaf(q4, bflo(ukX.z), da);
                db = fmaf(q5, bfhi(ukX.z), db);
                da = fmaf(q6, bflo(ukX.w), da);
                db = fmaf(q7, bfhi(ukX.w), db);
                float part = da + db;
                part += __shfl_xor(part, 1);
                part += __shfl_xor(part, 2);
                float a = fmaf(part, ATTN_SCALE, ebX);
                a = (a >= 0.f) ? a : 0.2f * a;
                const float w = ok ? __expf(a) : 0.f;
                ssX += w;
                x0 = fmaf(w, bflo(uvX.x), x0);
                x1 = fmaf(w, bfhi(uvX.x), x1);
                x2 = fmaf(w, bflo(uvX.y), x2);
                x3 = fmaf(w, bfhi(uvX.y), x3);
                x4 = fmaf(w, bflo(uvX.z), x4);
                x5 = fmaf(w, bfhi(uvX.z), x5);
                x6 = fmaf(w, bflo(uvX.w), x6);
                x7 = fmaf(w, bfhi(uvX.w), x7);
            }
            // ---- chain Y (edges p+4..p+7)
            {
                const bool ok = (p + 4 + g) < end;
                float da = q0 * bflo(ukY.x);
                float db = q1 * bfhi(ukY.x);
                da = fmaf(q2, bflo(ukY.y), da);
                db = fmaf(q3, bfhi(ukY.y), db);
                da = fmaf(q4, bflo(ukY.z), da);
                db = fmaf(q5, bfhi(ukY.z), db);
                da = fmaf(q6, bflo(ukY.w), da);
                db = fmaf(q7, bfhi(ukY.w), db);
                float part = da + db;
                part += __shfl_xor(part, 1);
                part += __shfl_xor(part, 2);
                float a = fmaf(part, ATTN_SCALE, ebY);
                a = (a >= 0.f) ? a : 0.2f * a;
                const float w = ok ? __expf(a) : 0.f;
                ssY += w;
                y0 = fmaf(w, bflo(uvY.x), y0);
                y1 = fmaf(w, bfhi(uvY.x), y1);
                y2 = fmaf(w, bflo(uvY.y), y2);
                y3 = fmaf(w, bfhi(uvY.y), y3);
                y4 = fmaf(w, bflo(uvY.z), y4);
                y5 = fmaf(w, bfhi(uvY.z), y5);
                y6 = fmaf(w, bflo(uvY.w), y6);
                y7 = fmaf(w, bfhi(uvY.w), y7);
            }
            sX = sXn; sY = sYn; ebX = ebXn; ebY = ebYn;
        }
    }

    // merge chains, then cross-group reduction (once per node)
    float ss = ssX + ssY;
    float a0 = x0 + y0, a1 = x1 + y1, a2 = x2 + y2, a3 = x3 + y3;
    float a4 = x4 + y4, a5 = x5 + y5, a6 = x6 + y6, a7 = x7 + y7;

    ss += __shfl_xor(ss, 16);
    ss += __shfl_xor(ss, 32);
    a0 += __shfl_xor(a0, 16); a0 += __shfl_xor(a0, 32);
    a1 += __shfl_xor(a1, 16); a1 += __shfl_xor(a1, 32);
    a2 += __shfl_xor(a2, 16); a2 += __shfl_xor(a2, 32);
    a3 += __shfl_xor(a3, 16); a3 += __shfl_xor(a3, 32);
    a4 += __shfl_xor(a4, 16); a4 += __shfl_xor(a4, 32);
    a5 += __shfl_xor(a5, 16); a5 += __shfl_xor(a5, 32);
    a6 += __shfl_xor(a6, 16); a6 += __shfl_xor(a6, 32);
    a7 += __shfl_xor(a7, 16); a7 += __shfl_xor(a7, 32);

    if (g == 0) {
        const float inv = 1.f / fmaxf(ss, 1e-12f);
        uint4 o;
        o.x = (uint)f2bf(a0 * inv) | ((uint)f2bf(a1 * inv) << 16);
        o.y = (uint)f2bf(a2 * inv) | ((uint)f2bf(a3 * inv) << 16);
        o.z = (uint)f2bf(a4 * inv) | ((uint)f2bf(a5 * inv) << 16);
        o.w = (uint)f2bf(a6 * inv) | ((uint)f2bf(a7 * inv) << 16);
        *(uint4*)(aggb + (size_t)d * DIM + 8 * t) = o;
    }
}

// ----------------------------------------------------------------- launch
extern "C" void kernel_launch(void* const* d_in, const int* in_sizes, int n_in,
                              void* d_out, int out_size, void* d_ws, size_t ws_size,
                              hipStream_t stream)
{
    const float* x         = (const float*)d_in[0];
    const int*   edge_idx  = (const int*)d_in[1];   // [2,E]: row0=src, row1=dst
    const float* edge_attr = (const float*)d_in[2];
    const float* Wq        = (const float*)d_in[3];
    const float* Wk        = (const float*)d_in[4];
    const float* Wv        = (const float*)d_in[5];
    const float* We        = (const float*)d_in[6];
    const float* Wo        = (const float*)d_in[7];
    const float* bo        = (const float*)d_in[8];
    const float* Wm        = (const float*)d_in[9];
    const float* bm        = (const float*)d_in[10];
    float* out = (float*)d_out;

    const int* src = edge_idx;
    const int* dst = edge_idx + NE;

    // workspace layout
    ushort* xb   = (ushort*)d_ws;                 // 6,400,000 us
    ushort* Qb   = xb + (size_t)NN * DIM;         // 6,400,000 us
    ushort* Kb   = Qb + (size_t)NN * DIM;         // 6,400,000 us
    ushort* Vb   = Kb + (size_t)NN * DIM;         // 6,400,000 us
    ushort* aggb = Vb + (size_t)NN * DIM;         // 6,400,000 us
    int*   psrc     = (int*)(aggb + (size_t)NN * DIM);  // 800,000 i
    int*   pdst     = psrc + NE;                  // 800,000 i
    float* peb      = (float*)(pdst + NE);        // 3,200,000 f
    float* eb_csr   = peb + (size_t)EH;           // 3,200,000 f
    float* Wx       = eb_csr + (size_t)EH;        // 16,384 f
    float* bprime   = Wx + 16384;                 // 128 f
    short* BpQKV    = (short*)(bprime + 128);     // 49,152 s
    short* BpOut    = BpQKV + 49152;              // 32,768 s
    int*   rowptr   = (int*)(BpOut + 32768);      // 50,048 i (50001 used)
    int*   srcp     = rowptr + 50048;             // 800,000 i
    int*   bkt_cnt    = srcp + NE;                // 128 i
    int*   bkt_base   = bkt_cnt + 128;            // 128 i (NBKT+1 used)
    int*   bkt_cursor = bkt_base + 128;           // 128 i

    // prep: bf16 x (+ bkt_cnt zero), fused epilogue weights, packed B operands
    prep_x_kernel<<<(NN * DIM / 4) / 256, 256, 0, stream>>>(x, xb, bkt_cnt);
    prep_wxb_kernel<<<129, 128, 0, stream>>>(Wo, Wm, bo, bm, Wx, bprime);
    pack_qkv_kernel<<<192, 256, 0, stream>>>(Wq, Wk, Wv, BpQKV);
    pack_out_kernel<<<128, 256, 0, stream>>>(Wm, Wx, BpOut);

    // CSR build — bucketed two-phase sort, no global random scatter
    bkt_hist_kernel<<<HBLKS, 256, 0, stream>>>(dst, bkt_cnt);
    bkt_scan_kernel<<<1, 64, 0, stream>>>(bkt_cnt, bkt_base, bkt_cursor, rowptr);
    partition_kernel<<<PBLKS, 256, 0, stream>>>(src, dst, edge_attr, We,
                                                bkt_cursor, psrc, pdst, peb);
    bucket_csr_kernel<<<NBKT, 256, 0, stream>>>(bkt_base, psrc, pdst, peb,
                                                rowptr, srcp, eb_csr);

    // main pipeline
    qkv_mfma_kernel<<<GEMM_BLOCKS, 256, 0, stream>>>(xb, BpQKV, Qb, Kb, Vb);
    attn_agg_kernel<<<NN / 4, 256, 0, stream>>>(Qb, Kb, Vb, rowptr, srcp,
                                                eb_csr, aggb);
    out_mfma_kernel<<<GEMM_BLOCKS, 256, 0, stream>>>(xb, aggb, BpOut, bprime, out);
}

// Round 4
// 254.076 us; speedup vs baseline: 1.1768x; 1.0964x over previous
//
#include <hip/hip_runtime.h>
#include <hip/hip_bf16.h>
#include <math.h>

#define NN 50000
#define NE 800000
#define DIM 128
#define NH 4
#define HD 32
#define ATTN_SCALE 0.17677669529663687f   // 1/sqrt(32)
#define MTILE 64
#define GEMM_BLOCKS 782       // ceil(50000/64)
#define NBKT 98               // buckets of 512 nodes: dst>>9
#define PTS 2048              // edges per partition block
#define HBLKS 104             // hist blocks: shallow atomic chains

// fused prep grid ranges
#define PREP_QKV_BASE  104        // 192 blocks
#define PREP_WXB_BASE  296        // 65 blocks (2 rows each, 130 rows)
#define PREP_X_BASE    361        // 6250 blocks
#define PREP_GRID      6611

// fused partition + qkv + pack_out grid ranges
#define PQ_PART_N   391           // ceil(NE/PTS)
#define PQ_QKV_BASE 391           // 782 blocks
#define PQ_PACKO_BASE 1173        // 128 blocks
#define PQ_GRID     1301

typedef unsigned int uint;
typedef unsigned short ushort;
typedef __attribute__((ext_vector_type(8))) short short8;   // 8 bf16 (4 VGPRs)
typedef __attribute__((ext_vector_type(4))) float f32x4;    // MFMA acc

__device__ inline ushort f2bf(float f) {
    __hip_bfloat16 h = __float2bfloat16(f);   // round-to-nearest
    return *(ushort*)&h;
}
__device__ inline float bflo(uint u) { return __uint_as_float(u << 16); }
__device__ inline float bfhi(uint u) { return __uint_as_float(u & 0xffff0000u); }
__device__ inline float bf2f(ushort u) { return __uint_as_float((uint)u << 16); }

// ------------------------------------------------------------ fused prep
// blockIdx ranges: [0,104) bkt hist | [104,296) pack_qkv |
// [296,361) Wx/b' | [361,6611) x->bf16.  bkt_cnt pre-zeroed by memset.
__global__ __launch_bounds__(256) void prep_all_kernel(
    const float* __restrict__ x, ushort* __restrict__ xb,
    const int* __restrict__ dst, int* __restrict__ bkt_cnt,
    const float* __restrict__ Wq, const float* __restrict__ Wk,
    const float* __restrict__ Wv, short* __restrict__ BpQKV,
    const float* __restrict__ Wo, const float* __restrict__ Wm,
    const float* __restrict__ bo, const float* __restrict__ bm,
    float* __restrict__ Wx, float* __restrict__ bprime)
{
    const int bid = blockIdx.x;
    const int tid = threadIdx.x;

    if (bid < PREP_QKV_BASE) {
        __shared__ int c[NBKT];
        if (tid < NBKT) c[tid] = 0;
        __syncthreads();
        for (int e = bid * 256 + tid; e < NE; e += HBLKS * 256)
            atomicAdd(&c[dst[e] >> 9], 1);
        __syncthreads();
        if (tid < NBKT && c[tid]) atomicAdd(&bkt_cnt[tid], c[tid]);
    } else if (bid < PREP_WXB_BASE) {
        const int idx = (bid - PREP_QKV_BASE) * 256 + tid;   // < 49152
        const int j = idx & 7, lane = (idx >> 3) & 63;
        const int rest = idx >> 9;                           // kc*24 + nt
        const int nt = rest % 24, kc = rest / 24;
        const int k = kc * 32 + (lane >> 4) * 8 + j;
        const int n = nt * 16 + (lane & 15);
        const float* W = (n < 128) ? Wq : (n < 256 ? Wk : Wv);
        BpQKV[idx] = (short)f2bf(W[k * 128 + (n & 127)]);
    } else if (bid < PREP_X_BASE) {
        const int r = (bid - PREP_WXB_BASE) * 2 + (tid >> 7);
        const int j = tid & 127;
        if (r < 128) {
            float acc = 0.f;
            for (int t = 0; t < 128; ++t)
                acc = fmaf(Wo[r * 128 + t], Wm[(128 + t) * 128 + j], acc);
            Wx[r * 128 + j] = acc;
        } else if (r == 128) {
            float acc = bm[j];
            for (int t = 0; t < 128; ++t)
                acc = fmaf(bo[t], Wm[(128 + t) * 128 + j], acc);
            bprime[j] = acc;
        }
    } else {
        const int i = (bid - PREP_X_BASE) * 256 + tid;       // < 1,600,000
        const float4 v = ((const float4*)x)[i];
        ushort4 o;
        o.x = f2bf(v.x); o.y = f2bf(v.y); o.z = f2bf(v.z); o.w = f2bf(v.w);
        ((ushort4*)xb)[i] = o;
    }
}

__global__ void bkt_scan_kernel(const int* __restrict__ bkt_cnt,
                                int* __restrict__ bkt_base,
                                int* __restrict__ bkt_cursor,
                                int* __restrict__ rowptr)
{
    if (threadIdx.x == 0) {
        int run = 0;
        for (int b = 0; b < NBKT; ++b) {
            bkt_base[b] = run;
            bkt_cursor[b] = run;
            run += bkt_cnt[b];
        }
        bkt_base[NBKT] = run;   // == NE
        rowptr[NN] = run;
    }
}

// --------------------------------- fused partition + QKV MFMA + pack_out
__global__ __launch_bounds__(256) void partqkv_kernel(
    const int* __restrict__ src, const int* __restrict__ dst,
    const float* __restrict__ edge_attr, const float* __restrict__ We,
    int* __restrict__ bkt_cursor,
    uint* __restrict__ ppack, uint2* __restrict__ pebp,
    const ushort* __restrict__ xb, const short* __restrict__ BpQKV,
    ushort* __restrict__ Qb, ushort* __restrict__ Kb, ushort* __restrict__ Vb,
    const float* __restrict__ Wm, const float* __restrict__ Wx,
    short* __restrict__ BpOut)
{
    const int bid = blockIdx.x;
    const int tid = threadIdx.x;

    if (bid < PQ_PART_N) {
        __shared__ int cnt[NBKT], rbase[NBKT], cnt2[NBKT];
        if (tid < NBKT) cnt[tid] = 0;
        __syncthreads();
        const int e0 = bid * PTS;
        #pragma unroll
        for (int it = 0; it < 8; ++it) {
            const int e = e0 + it * 256 + tid;
            if (e < NE) atomicAdd(&cnt[dst[e] >> 9], 1);
        }
        __syncthreads();
        if (tid < NBKT) {
            rbase[tid] = cnt[tid] ? atomicAdd(&bkt_cursor[tid], cnt[tid]) : 0;
            cnt2[tid] = 0;
        }
        __syncthreads();
        #pragma unroll
        for (int it = 0; it < 8; ++it) {
            const int e = e0 + it * 256 + tid;
            if (e < NE) {
                const int d = dst[e];
                const int b = d >> 9;
                const int r = atomicAdd(&cnt2[b], 1);
                const int pos = rbase[b] + r;
                ppack[pos] = (uint)src[e] | ((uint)(d & 511) << 16);
                const float a0 = edge_attr[e * 3 + 0];
                const float a1 = edge_attr[e * 3 + 1];
                const float a2 = edge_attr[e * 3 + 2];
                const float b0 = a0 * We[0] + a1 * We[4] + a2 * We[8];
                const float b1 = a0 * We[1] + a1 * We[5] + a2 * We[9];
                const float b2 = a0 * We[2] + a1 * We[6] + a2 * We[10];
                const float b3 = a0 * We[3] + a1 * We[7] + a2 * We[11];
                uint2 ep;
                ep.x = (uint)f2bf(b0) | ((uint)f2bf(b1) << 16);
                ep.y = (uint)f2bf(b2) | ((uint)f2bf(b3) << 16);
                pebp[pos] = ep;
            }
        }
    } else if (bid < PQ_PACKO_BASE) {
        const int qb = bid - PQ_QKV_BASE;
        const int wave = tid >> 6;
        const int lane = tid & 63;
        const int m = lane & 15, quad = lane >> 4;
        const int row0w = qb * MTILE + wave * 16;
        const int arow = row0w + m;
        const bool rowok = arow < NN;

        short8 a[4];
        #pragma unroll
        for (int kc = 0; kc < 4; ++kc)
            a[kc] = rowok ? *(const short8*)(xb + (size_t)arow * 128 + kc * 32 + quad * 8)
                          : (short8)(0);

        const int NT = 24;
        for (int nt = 0; nt < NT; nt += 2) {
            f32x4 acc0 = {0.f, 0.f, 0.f, 0.f}, acc1 = {0.f, 0.f, 0.f, 0.f};
            #pragma unroll
            for (int kc = 0; kc < 4; ++kc) {
                const short8 b0 = *(const short8*)(BpQKV + ((size_t)(kc * NT + nt) * 64 + lane) * 8);
                const short8 b1 = *(const short8*)(BpQKV + ((size_t)(kc * NT + nt + 1) * 64 + lane) * 8);
                acc0 = __builtin_amdgcn_mfma_f32_16x16x32_bf16(a[kc], b0, acc0, 0, 0, 0);
                acc1 = __builtin_amdgcn_mfma_f32_16x16x32_bf16(a[kc], b1, acc1, 0, 0, 0);
            }
            #pragma unroll
            for (int t = 0; t < 2; ++t) {
                const f32x4 acc = t ? acc1 : acc0;
                const int c = (nt + t) * 16 + m;           // global col in [0,384)
                ushort* dstp_ = (c < 128) ? Qb : (c < 256 ? Kb : Vb);
                const int lc = c & 127;
                #pragma unroll
                for (int g = 0; g < 4; ++g) {
                    const int r = row0w + quad * 4 + g;
                    if (r < NN) dstp_[(size_t)r * 128 + lc] = f2bf(acc[g]);
                }
            }
        }
    } else {
        const int idx = (bid - PQ_PACKO_BASE) * 256 + tid;   // < 32768
        const int j = idx & 7, lane = (idx >> 3) & 63;
        const int rest = idx >> 9;                           // kc*8 + nt
        const int nt = rest & 7, kc = rest >> 3;
        const int k = kc * 32 + (lane >> 4) * 8 + j;
        const int n = nt * 16 + (lane & 15);
        const float v = (k < 128) ? Wm[k * 128 + n] : Wx[(k - 128) * 128 + n];
        BpOut[idx] = (short)f2bf(v);
    }
}

// Phase 2: one block per bucket; scatter 16-bit src + bf16x4 edge bias.
__global__ __launch_bounds__(256) void bucket_csr_kernel(
    const int* __restrict__ bkt_base,
    const uint* __restrict__ ppack, const uint2* __restrict__ pebp,
    int* __restrict__ rowptr,
    ushort* __restrict__ srcp, uint2* __restrict__ ebq)
{
    __shared__ int cnt[512];
    __shared__ int pre[512];
    __shared__ int sc[256];
    const int tid = threadIdx.x;
    const int b = blockIdx.x;
    const int base = bkt_base[b];
    const int n = bkt_base[b + 1] - base;
    const int node0 = b << 9;

    cnt[tid] = 0; cnt[tid + 256] = 0;
    __syncthreads();
    for (int i = base + tid; i < base + n; i += 256)
        atomicAdd(&cnt[ppack[i] >> 16], 1);
    __syncthreads();

    const int pair = cnt[2 * tid] + cnt[2 * tid + 1];
    sc[tid] = pair;
    __syncthreads();
    for (int off = 1; off < 256; off <<= 1) {
        const int v = (tid >= off) ? sc[tid - off] : 0;
        __syncthreads();
        sc[tid] += v;
        __syncthreads();
    }
    const int ex = sc[tid] - pair;
    pre[2 * tid] = base + ex;
    pre[2 * tid + 1] = base + ex + cnt[2 * tid];
    __syncthreads();

    for (int l = tid; l < 512; l += 256) {
        const int g = node0 + l;
        if (g < NN) rowptr[g] = pre[l];
    }
    __syncthreads();

    for (int i = base + tid; i < base + n; i += 256) {
        const uint v = ppack[i];
        const int pos = atomicAdd(&pre[v >> 16], 1);
        srcp[pos] = (ushort)(v & 0xFFFFu);
        ebq[pos] = pebp[i];
    }
}

// ---------------------------------------------------------------- OUT MFMA
__global__ __launch_bounds__(256) void out_mfma_kernel(
    const ushort* __restrict__ xb, const ushort* __restrict__ aggb,
    const short* __restrict__ Bp, const float* __restrict__ bprime,
    float* __restrict__ out)
{
    const int wave = threadIdx.x >> 6;
    const int lane = threadIdx.x & 63;
    const int m = lane & 15, quad = lane >> 4;
    const int row0w = blockIdx.x * MTILE + wave * 16;
    const int arow = row0w + m;
    const bool rowok = arow < NN;

    short8 a[8];
    #pragma unroll
    for (int kc = 0; kc < 4; ++kc)
        a[kc] = rowok ? *(const short8*)(xb + (size_t)arow * 128 + kc * 32 + quad * 8)
                      : (short8)(0);
    #pragma unroll
    for (int kc = 0; kc < 4; ++kc)
        a[4 + kc] = rowok ? *(const short8*)(aggb + (size_t)arow * 128 + kc * 32 + quad * 8)
                          : (short8)(0);

    const int NT = 8;
    for (int nt = 0; nt < NT; nt += 2) {
        f32x4 acc0 = {0.f, 0.f, 0.f, 0.f}, acc1 = {0.f, 0.f, 0.f, 0.f};
        #pragma unroll
        for (int kc = 0; kc < 8; ++kc) {
            const short8 b0 = *(const short8*)(Bp + ((size_t)(kc * NT + nt) * 64 + lane) * 8);
            const short8 b1 = *(const short8*)(Bp + ((size_t)(kc * NT + nt + 1) * 64 + lane) * 8);
            acc0 = __builtin_amdgcn_mfma_f32_16x16x32_bf16(a[kc], b0, acc0, 0, 0, 0);
            acc1 = __builtin_amdgcn_mfma_f32_16x16x32_bf16(a[kc], b1, acc1, 0, 0, 0);
        }
        #pragma unroll
        for (int t = 0; t < 2; ++t) {
            const f32x4 acc = t ? acc1 : acc0;
            const int c = (nt + t) * 16 + m;           // global col in [0,128)
            const float bb = bprime[c];
            #pragma unroll
            for (int g = 0; g < 4; ++g) {
                const int r = row0w + quad * 4 + g;
                if (r < NN) out[(size_t)r * 128 + c] = fmaxf(acc[g] + bb, 0.f);
            }
        }
    }
}

// ----------------------------------------- FUSED attn + softmax + aggregate
__global__ __launch_bounds__(256) void attn_agg_kernel(
    const ushort* __restrict__ Qb, const ushort* __restrict__ Kb,
    const ushort* __restrict__ Vb,
    const int* __restrict__ rowptr, const ushort* __restrict__ srcp,
    const ushort* __restrict__ ebb, ushort* __restrict__ aggb)
{
    const int tid = threadIdx.x;
    const int d = blockIdx.x * 4 + (tid >> 6);
    const int lane = tid & 63;
    const int g = lane >> 4;          // edge slot within quad
    const int t = lane & 15;          // 8-dim chunk index
    const int h = t >> 2;             // head of this chunk
    const int begin = rowptr[d];
    const int end   = rowptr[d + 1];

    const uint4 uq = *(const uint4*)(Qb + (size_t)d * DIM + 8 * t);
    const float q0 = bflo(uq.x), q1 = bfhi(uq.x);
    const float q2 = bflo(uq.y), q3 = bfhi(uq.y);
    const float q4 = bflo(uq.z), q5 = bfhi(uq.z);
    const float q6 = bflo(uq.w), q7 = bfhi(uq.w);

    float ss = 0.f;
    float a0 = 0.f, a1 = 0.f, a2 = 0.f, a3 = 0.f;
    float a4 = 0.f, a5 = 0.f, a6 = 0.f, a7 = 0.f;

    if (begin < end) {
        int ec = begin + g;
        if (ec >= end) ec = end - 1;
        int s    = (int)srcp[ec];
        float eb = bf2f(ebb[ec * 4 + h]);

        for (int p = begin; p < end; p += 4) {
            const bool ok = (p + g) < end;
            const int pn = p + 4;
            int sn = s; float ebn = eb;
            if (pn < end) {
                int en = pn + g;
                if (en >= end) en = end - 1;
                sn  = (int)srcp[en];
                ebn = bf2f(ebb[en * 4 + h]);
            }

            const uint4 uk = *(const uint4*)(Kb + (size_t)s * DIM + 8 * t);
            const uint4 uv = *(const uint4*)(Vb + (size_t)s * DIM + 8 * t);

            float da = q0 * bflo(uk.x);
            float db = q1 * bfhi(uk.x);
            da = fmaf(q2, bflo(uk.y), da);
            db = fmaf(q3, bfhi(uk.y), db);
            da = fmaf(q4, bflo(uk.z), da);
            db = fmaf(q5, bfhi(uk.z), db);
            da = fmaf(q6, bflo(uk.w), da);
            db = fmaf(q7, bfhi(uk.w), db);
            float part = da + db;
            part += __shfl_xor(part, 1);
            part += __shfl_xor(part, 2);

            float a = fmaf(part, ATTN_SCALE, eb);
            a = (a >= 0.f) ? a : 0.2f * a;
            float w = ok ? __expf(a) : 0.f;

            ss += w;
            a0 = fmaf(w, bflo(uv.x), a0);
            a1 = fmaf(w, bfhi(uv.x), a1);
            a2 = fmaf(w, bflo(uv.y), a2);
            a3 = fmaf(w, bfhi(uv.y), a3);
            a4 = fmaf(w, bflo(uv.z), a4);
            a5 = fmaf(w, bfhi(uv.z), a5);
            a6 = fmaf(w, bflo(uv.w), a6);
            a7 = fmaf(w, bfhi(uv.w), a7);

            s = sn; eb = ebn;
        }
    }

    ss += __shfl_xor(ss, 16);
    ss += __shfl_xor(ss, 32);
    a0 += __shfl_xor(a0, 16); a0 += __shfl_xor(a0, 32);
    a1 += __shfl_xor(a1, 16); a1 += __shfl_xor(a1, 32);
    a2 += __shfl_xor(a2, 16); a2 += __shfl_xor(a2, 32);
    a3 += __shfl_xor(a3, 16); a3 += __shfl_xor(a3, 32);
    a4 += __shfl_xor(a4, 16); a4 += __shfl_xor(a4, 32);
    a5 += __shfl_xor(a5, 16); a5 += __shfl_xor(a5, 32);
    a6 += __shfl_xor(a6, 16); a6 += __shfl_xor(a6, 32);
    a7 += __shfl_xor(a7, 16); a7 += __shfl_xor(a7, 32);

    if (g == 0) {
        const float inv = 1.f / fmaxf(ss, 1e-12f);
        uint4 o;
        o.x = (uint)f2bf(a0 * inv) | ((uint)f2bf(a1 * inv) << 16);
        o.y = (uint)f2bf(a2 * inv) | ((uint)f2bf(a3 * inv) << 16);
        o.z = (uint)f2bf(a4 * inv) | ((uint)f2bf(a5 * inv) << 16);
        o.w = (uint)f2bf(a6 * inv) | ((uint)f2bf(a7 * inv) << 16);
        *(uint4*)(aggb + (size_t)d * DIM + 8 * t) = o;
    }
}

// ----------------------------------------------------------------- launch
extern "C" void kernel_launch(void* const* d_in, const int* in_sizes, int n_in,
                              void* d_out, int out_size, void* d_ws, size_t ws_size,
                              hipStream_t stream)
{
    const float* x         = (const float*)d_in[0];
    const int*   edge_idx  = (const int*)d_in[1];   // [2,E]: row0=src, row1=dst
    const float* edge_attr = (const float*)d_in[2];
    const float* Wq        = (const float*)d_in[3];
    const float* Wk        = (const float*)d_in[4];
    const float* Wv        = (const float*)d_in[5];
    const float* We        = (const float*)d_in[6];
    const float* Wo        = (const float*)d_in[7];
    const float* bo        = (const float*)d_in[8];
    const float* Wm        = (const float*)d_in[9];
    const float* bm        = (const float*)d_in[10];
    float* out = (float*)d_out;

    const int* src = edge_idx;
    const int* dst = edge_idx + NE;

    // workspace layout
    ushort* xb   = (ushort*)d_ws;                 // NN*DIM us
    ushort* Qb   = xb + (size_t)NN * DIM;
    ushort* Kb   = Qb + (size_t)NN * DIM;
    ushort* Vb   = Kb + (size_t)NN * DIM;
    ushort* aggb = Vb + (size_t)NN * DIM;
    uint*  ppack = (uint*)(aggb + (size_t)NN * DIM);   // NE uints
    uint2* pebp  = (uint2*)(ppack + NE);               // NE uint2 (bf16x4 eb)
    uint2* ebq   = pebp + NE;                          // NE uint2 (CSR order)
    ushort* srcp = (ushort*)(ebq + NE);                // NE ushorts
    float* Wx    = (float*)(srcp + NE);                // 16,384 f
    float* bprime= Wx + 16384;                         // 128 f
    short* BpQKV = (short*)(bprime + 128);             // 49,152 s
    short* BpOut = BpQKV + 49152;                      // 32,768 s
    int*   rowptr= (int*)(BpOut + 32768);              // 50,048 i (50001 used)
    int*   bkt_cnt    = rowptr + 50048;                // 128 i
    int*   bkt_base   = bkt_cnt + 128;                 // 128 i (NBKT+1 used)
    int*   bkt_cursor = bkt_base + 128;                // 128 i

    hipMemsetAsync(bkt_cnt, 0, 128 * sizeof(int), stream);

    prep_all_kernel<<<PREP_GRID, 256, 0, stream>>>(
        x, xb, dst, bkt_cnt, Wq, Wk, Wv, BpQKV, Wo, Wm, bo, bm, Wx, bprime);

    bkt_scan_kernel<<<1, 64, 0, stream>>>(bkt_cnt, bkt_base, bkt_cursor, rowptr);

    partqkv_kernel<<<PQ_GRID, 256, 0, stream>>>(
        src, dst, edge_attr, We, bkt_cursor, ppack, pebp,
        xb, BpQKV, Qb, Kb, Vb, Wm, Wx, BpOut);

    bucket_csr_kernel<<<NBKT, 256, 0, stream>>>(bkt_base, ppack, pebp,
                                                rowptr, srcp, ebq);

    attn_agg_kernel<<<NN / 4, 256, 0, stream>>>(Qb, Kb, Vb, rowptr, srcp,
                                                (const ushort*)ebq, aggb);

    out_mfma_kernel<<<GEMM_BLOCKS, 256, 0, stream>>>(xb, aggb, BpOut, bprime, out);
}

// Round 5
// 249.290 us; speedup vs baseline: 1.1994x; 1.0192x over previous
//
#include <hip/hip_runtime.h>
#include <hip/hip_bf16.h>
#include <math.h>

#define NN 50000
#define NE 800000
#define DIM 128
#define NH 4
#define HD 32
#define ATTN_SCALE 0.17677669529663687f   // 1/sqrt(32)
#define MTILE 64
#define GEMM_BLOCKS 782       // ceil(50000/64)
#define NBKT 98               // parent buckets of 512 nodes: dst>>9
#define PTS 2048              // edges per partition block
#define HBLKS 104             // hist blocks: shallow atomic chains

// fused prep grid ranges
#define PREP_QKV_BASE  104        // 192 blocks
#define PREP_WXB_BASE  296        // 65 blocks (2 rows each, 130 rows)
#define PREP_X_BASE    361        // 6250 blocks
#define PREP_GRID      6611

// fused partition + pack_out grid ranges
#define PART_N      391           // ceil(NE/PTS)
#define PART_GRID   519           // + 128 pack_out blocks

// fused csr-split + qkv gemm grid ranges
#define CSR_N       782           // 8 sub-blocks per parent bucket (64 nodes each)
#define CSRQ_GRID   1564          // + 782 GEMM blocks

typedef unsigned int uint;
typedef unsigned short ushort;
typedef __attribute__((ext_vector_type(8))) short short8;   // 8 bf16 (4 VGPRs)
typedef __attribute__((ext_vector_type(4))) float f32x4;    // MFMA acc

__device__ inline ushort f2bf(float f) {
    __hip_bfloat16 h = __float2bfloat16(f);   // round-to-nearest
    return *(ushort*)&h;
}
__device__ inline float bflo(uint u) { return __uint_as_float(u << 16); }
__device__ inline float bfhi(uint u) { return __uint_as_float(u & 0xffff0000u); }
__device__ inline float bf2f(ushort u) { return __uint_as_float((uint)u << 16); }

// ------------------------------------------------------------ fused prep
// blockIdx ranges: [0,104) bkt hist | [104,296) pack_qkv |
// [296,361) Wx/b' | [361,6611) x->bf16.  bkt_cnt pre-zeroed by memset.
__global__ __launch_bounds__(256) void prep_all_kernel(
    const float* __restrict__ x, ushort* __restrict__ xb,
    const int* __restrict__ dst, int* __restrict__ bkt_cnt,
    const float* __restrict__ Wq, const float* __restrict__ Wk,
    const float* __restrict__ Wv, short* __restrict__ BpQKV,
    const float* __restrict__ Wo, const float* __restrict__ Wm,
    const float* __restrict__ bo, const float* __restrict__ bm,
    float* __restrict__ Wx, float* __restrict__ bprime)
{
    const int bid = blockIdx.x;
    const int tid = threadIdx.x;

    if (bid < PREP_QKV_BASE) {
        __shared__ int c[NBKT];
        if (tid < NBKT) c[tid] = 0;
        __syncthreads();
        for (int e = bid * 256 + tid; e < NE; e += HBLKS * 256)
            atomicAdd(&c[dst[e] >> 9], 1);
        __syncthreads();
        if (tid < NBKT && c[tid]) atomicAdd(&bkt_cnt[tid], c[tid]);
    } else if (bid < PREP_WXB_BASE) {
        const int idx = (bid - PREP_QKV_BASE) * 256 + tid;   // < 49152
        const int j = idx & 7, lane = (idx >> 3) & 63;
        const int rest = idx >> 9;                           // kc*24 + nt
        const int nt = rest % 24, kc = rest / 24;
        const int k = kc * 32 + (lane >> 4) * 8 + j;
        const int n = nt * 16 + (lane & 15);
        const float* W = (n < 128) ? Wq : (n < 256 ? Wk : Wv);
        BpQKV[idx] = (short)f2bf(W[k * 128 + (n & 127)]);
    } else if (bid < PREP_X_BASE) {
        const int r = (bid - PREP_WXB_BASE) * 2 + (tid >> 7);
        const int j = tid & 127;
        if (r < 128) {
            float acc = 0.f;
            for (int t = 0; t < 128; ++t)
                acc = fmaf(Wo[r * 128 + t], Wm[(128 + t) * 128 + j], acc);
            Wx[r * 128 + j] = acc;
        } else if (r == 128) {
            float acc = bm[j];
            for (int t = 0; t < 128; ++t)
                acc = fmaf(bo[t], Wm[(128 + t) * 128 + j], acc);
            bprime[j] = acc;
        }
    } else {
        const int i = (bid - PREP_X_BASE) * 256 + tid;       // < 1,600,000
        const float4 v = ((const float4*)x)[i];
        ushort4 o;
        o.x = f2bf(v.x); o.y = f2bf(v.y); o.z = f2bf(v.z); o.w = f2bf(v.w);
        ((ushort4*)xb)[i] = o;
    }
}

__global__ void bkt_scan_kernel(const int* __restrict__ bkt_cnt,
                                int* __restrict__ bkt_base,
                                int* __restrict__ bkt_cursor,
                                int* __restrict__ rowptr)
{
    if (threadIdx.x == 0) {
        int run = 0;
        for (int b = 0; b < NBKT; ++b) {
            bkt_base[b] = run;
            bkt_cursor[b] = run;
            run += bkt_cnt[b];
        }
        bkt_base[NBKT] = run;   // == NE
        rowptr[NN] = run;
    }
}

// --------------------------------------- fused partition + pack_out
__global__ __launch_bounds__(256) void part_kernel(
    const int* __restrict__ src, const int* __restrict__ dst,
    const float* __restrict__ edge_attr, const float* __restrict__ We,
    int* __restrict__ bkt_cursor,
    uint* __restrict__ ppack, uint2* __restrict__ pebp,
    const float* __restrict__ Wm, const float* __restrict__ Wx,
    short* __restrict__ BpOut)
{
    const int bid = blockIdx.x;
    const int tid = threadIdx.x;

    if (bid < PART_N) {
        __shared__ int cnt[NBKT], rbase[NBKT], cnt2[NBKT];
        if (tid < NBKT) cnt[tid] = 0;
        __syncthreads();
        const int e0 = bid * PTS;
        #pragma unroll
        for (int it = 0; it < 8; ++it) {
            const int e = e0 + it * 256 + tid;
            if (e < NE) atomicAdd(&cnt[dst[e] >> 9], 1);
        }
        __syncthreads();
        if (tid < NBKT) {
            rbase[tid] = cnt[tid] ? atomicAdd(&bkt_cursor[tid], cnt[tid]) : 0;
            cnt2[tid] = 0;
        }
        __syncthreads();
        #pragma unroll
        for (int it = 0; it < 8; ++it) {
            const int e = e0 + it * 256 + tid;
            if (e < NE) {
                const int d = dst[e];
                const int b = d >> 9;
                const int r = atomicAdd(&cnt2[b], 1);
                const int pos = rbase[b] + r;
                ppack[pos] = (uint)src[e] | ((uint)(d & 511) << 16);
                const float a0 = edge_attr[e * 3 + 0];
                const float a1 = edge_attr[e * 3 + 1];
                const float a2 = edge_attr[e * 3 + 2];
                const float b0 = a0 * We[0] + a1 * We[4] + a2 * We[8];
                const float b1 = a0 * We[1] + a1 * We[5] + a2 * We[9];
                const float b2 = a0 * We[2] + a1 * We[6] + a2 * We[10];
                const float b3 = a0 * We[3] + a1 * We[7] + a2 * We[11];
                uint2 ep;
                ep.x = (uint)f2bf(b0) | ((uint)f2bf(b1) << 16);
                ep.y = (uint)f2bf(b2) | ((uint)f2bf(b3) << 16);
                pebp[pos] = ep;
            }
        }
    } else {
        // ---- pack epilogue B operand [Wm1; Wx]
        const int idx = (bid - PART_N) * 256 + tid;          // < 32768
        const int j = idx & 7, lane = (idx >> 3) & 63;
        const int rest = idx >> 9;                           // kc*8 + nt
        const int nt = rest & 7, kc = rest >> 3;
        const int k = kc * 32 + (lane >> 4) * 8 + j;
        const int n = nt * 16 + (lane & 15);
        const float v = (k < 128) ? Wm[k * 128 + n] : Wx[(k - 128) * 128 + n];
        BpOut[idx] = (short)f2bf(v);
    }
}

// ------------------------------ fused CSR-split (8 sub-blocks/parent) + QKV
// [0,782): sub-block j handles nodes [j*64, j*64+64) of parent j>>3.
//   Re-hists the full parent range (streaming 4B reads), scans 512 in LDS,
//   writes rowptr + scatters ONLY its own 64 nodes' edges.
// [782,1564): QKV GEMM (independent -> backfills CUs under the CSR blocks).
//   K and V interleaved per node: KVb row = [K 128 ushorts | V 128 ushorts].
__global__ __launch_bounds__(256) void csrqkv_kernel(
    const int* __restrict__ bkt_base,
    const uint* __restrict__ ppack, const uint2* __restrict__ pebp,
    int* __restrict__ rowptr,
    ushort* __restrict__ srcp, uint2* __restrict__ ebq,
    const ushort* __restrict__ xb, const short* __restrict__ BpQKV,
    ushort* __restrict__ Qb, ushort* __restrict__ KVb)
{
    const int bid = blockIdx.x;
    const int tid = threadIdx.x;

    if (bid < CSR_N) {
        __shared__ int cnt[512];
        __shared__ int pre[512];
        __shared__ int sc[256];
        const int parent = bid >> 3;
        const int sub    = bid & 7;
        const int base = bkt_base[parent];
        const int n = bkt_base[parent + 1] - base;
        const int node0 = parent << 9;

        cnt[tid] = 0; cnt[tid + 256] = 0;
        __syncthreads();
        for (int i = base + tid; i < base + n; i += 256)
            atomicAdd(&cnt[ppack[i] >> 16], 1);
        __syncthreads();

        // exclusive scan of 512 counters: pair-sum -> 256-scan -> expand
        const int pair = cnt[2 * tid] + cnt[2 * tid + 1];
        sc[tid] = pair;
        __syncthreads();
        for (int off = 1; off < 256; off <<= 1) {
            const int v = (tid >= off) ? sc[tid - off] : 0;
            __syncthreads();
            sc[tid] += v;
            __syncthreads();
        }
        const int ex = sc[tid] - pair;
        pre[2 * tid] = base + ex;
        pre[2 * tid + 1] = base + ex + cnt[2 * tid];
        __syncthreads();

        // rowptr for our own 64 nodes
        if (tid < 64) {
            const int l = sub * 64 + tid;
            const int g = node0 + l;
            if (g < NN) rowptr[g] = pre[l];
        }
        __syncthreads();

        // scatter only our own edges (pre consumed as cursor)
        for (int i = base + tid; i < base + n; i += 256) {
            const uint v = ppack[i];
            const int l = v >> 16;
            if ((l >> 6) == sub) {
                const int pos = atomicAdd(&pre[l], 1);
                srcp[pos] = (ushort)(v & 0xFFFFu);
                ebq[pos] = pebp[i];
            }
        }
    } else {
        // ---- QKV MFMA
        const int qb = bid - CSR_N;
        const int wave = tid >> 6;
        const int lane = tid & 63;
        const int m = lane & 15, quad = lane >> 4;
        const int row0w = qb * MTILE + wave * 16;
        const int arow = row0w + m;
        const bool rowok = arow < NN;

        short8 a[4];
        #pragma unroll
        for (int kc = 0; kc < 4; ++kc)
            a[kc] = rowok ? *(const short8*)(xb + (size_t)arow * 128 + kc * 32 + quad * 8)
                          : (short8)(0);

        const int NT = 24;
        for (int nt = 0; nt < NT; nt += 2) {
            f32x4 acc0 = {0.f, 0.f, 0.f, 0.f}, acc1 = {0.f, 0.f, 0.f, 0.f};
            #pragma unroll
            for (int kc = 0; kc < 4; ++kc) {
                const short8 b0 = *(const short8*)(BpQKV + ((size_t)(kc * NT + nt) * 64 + lane) * 8);
                const short8 b1 = *(const short8*)(BpQKV + ((size_t)(kc * NT + nt + 1) * 64 + lane) * 8);
                acc0 = __builtin_amdgcn_mfma_f32_16x16x32_bf16(a[kc], b0, acc0, 0, 0, 0);
                acc1 = __builtin_amdgcn_mfma_f32_16x16x32_bf16(a[kc], b1, acc1, 0, 0, 0);
            }
            #pragma unroll
            for (int t = 0; t < 2; ++t) {
                const f32x4 acc = t ? acc1 : acc0;
                const int c = (nt + t) * 16 + m;           // global col in [0,384)
                #pragma unroll
                for (int g = 0; g < 4; ++g) {
                    const int r = row0w + quad * 4 + g;
                    if (r < NN) {
                        if (c < 128) Qb[(size_t)r * 128 + c] = f2bf(acc[g]);
                        else        KVb[(size_t)r * 256 + (c - 128)] = f2bf(acc[g]);
                    }
                }
            }
        }
    }
}

// ---------------------------------------------------------------- OUT MFMA
__global__ __launch_bounds__(256) void out_mfma_kernel(
    const ushort* __restrict__ xb, const ushort* __restrict__ aggb,
    const short* __restrict__ Bp, const float* __restrict__ bprime,
    float* __restrict__ out)
{
    const int wave = threadIdx.x >> 6;
    const int lane = threadIdx.x & 63;
    const int m = lane & 15, quad = lane >> 4;
    const int row0w = blockIdx.x * MTILE + wave * 16;
    const int arow = row0w + m;
    const bool rowok = arow < NN;

    short8 a[8];
    #pragma unroll
    for (int kc = 0; kc < 4; ++kc)
        a[kc] = rowok ? *(const short8*)(xb + (size_t)arow * 128 + kc * 32 + quad * 8)
                      : (short8)(0);
    #pragma unroll
    for (int kc = 0; kc < 4; ++kc)
        a[4 + kc] = rowok ? *(const short8*)(aggb + (size_t)arow * 128 + kc * 32 + quad * 8)
                          : (short8)(0);

    const int NT = 8;
    for (int nt = 0; nt < NT; nt += 2) {
        f32x4 acc0 = {0.f, 0.f, 0.f, 0.f}, acc1 = {0.f, 0.f, 0.f, 0.f};
        #pragma unroll
        for (int kc = 0; kc < 8; ++kc) {
            const short8 b0 = *(const short8*)(Bp + ((size_t)(kc * NT + nt) * 64 + lane) * 8);
            const short8 b1 = *(const short8*)(Bp + ((size_t)(kc * NT + nt + 1) * 64 + lane) * 8);
            acc0 = __builtin_amdgcn_mfma_f32_16x16x32_bf16(a[kc], b0, acc0, 0, 0, 0);
            acc1 = __builtin_amdgcn_mfma_f32_16x16x32_bf16(a[kc], b1, acc1, 0, 0, 0);
        }
        #pragma unroll
        for (int t = 0; t < 2; ++t) {
            const f32x4 acc = t ? acc1 : acc0;
            const int c = (nt + t) * 16 + m;           // global col in [0,128)
            const float bb = bprime[c];
            #pragma unroll
            for (int g = 0; g < 4; ++g) {
                const int r = row0w + quad * 4 + g;
                if (r < NN) out[(size_t)r * 128 + c] = fmaxf(acc[g] + bb, 0.f);
            }
        }
    }
}

// ----------------------------------------- FUSED attn + softmax + aggregate
// One wave per node; 4 groups of 16 lanes, each group owns one edge.
// K|V interleaved (512B/node): one base address, adjacent segments.
__global__ __launch_bounds__(256) void attn_agg_kernel(
    const ushort* __restrict__ Qb, const ushort* __restrict__ KVb,
    const int* __restrict__ rowptr, const ushort* __restrict__ srcp,
    const ushort* __restrict__ ebb, ushort* __restrict__ aggb)
{
    const int tid = threadIdx.x;
    const int d = blockIdx.x * 4 + (tid >> 6);
    const int lane = tid & 63;
    const int g = lane >> 4;          // edge slot within quad
    const int t = lane & 15;          // 8-dim chunk index
    const int h = t >> 2;             // head of this chunk
    const int begin = rowptr[d];
    const int end   = rowptr[d + 1];

    const uint4 uq = *(const uint4*)(Qb + (size_t)d * DIM + 8 * t);
    const float q0 = bflo(uq.x), q1 = bfhi(uq.x);
    const float q2 = bflo(uq.y), q3 = bfhi(uq.y);
    const float q4 = bflo(uq.z), q5 = bfhi(uq.z);
    const float q6 = bflo(uq.w), q7 = bfhi(uq.w);

    float ss = 0.f;
    float a0 = 0.f, a1 = 0.f, a2 = 0.f, a3 = 0.f;
    float a4 = 0.f, a5 = 0.f, a6 = 0.f, a7 = 0.f;

    if (begin < end) {
        int ec = begin + g;
        if (ec >= end) ec = end - 1;
        int s    = (int)srcp[ec];
        float eb = bf2f(ebb[ec * 4 + h]);

        for (int p = begin; p < end; p += 4) {
            const bool ok = (p + g) < end;
            const int pn = p + 4;
            int sn = s; float ebn = eb;
            if (pn < end) {
                int en = pn + g;
                if (en >= end) en = end - 1;
                sn  = (int)srcp[en];
                ebn = bf2f(ebb[en * 4 + h]);
            }

            const ushort* kv = KVb + (size_t)s * 256 + 8 * t;
            const uint4 uk = *(const uint4*)(kv);
            const uint4 uv = *(const uint4*)(kv + 128);

            float da = q0 * bflo(uk.x);
            float db = q1 * bfhi(uk.x);
            da = fmaf(q2, bflo(uk.y), da);
            db = fmaf(q3, bfhi(uk.y), db);
            da = fmaf(q4, bflo(uk.z), da);
            db = fmaf(q5, bfhi(uk.z), db);
            da = fmaf(q6, bflo(uk.w), da);
            db = fmaf(q7, bfhi(uk.w), db);
            float part = da + db;
            part += __shfl_xor(part, 1);
            part += __shfl_xor(part, 2);

            float a = fmaf(part, ATTN_SCALE, eb);
            a = (a >= 0.f) ? a : 0.2f * a;
            float w = ok ? __expf(a) : 0.f;

            ss += w;
            a0 = fmaf(w, bflo(uv.x), a0);
            a1 = fmaf(w, bfhi(uv.x), a1);
            a2 = fmaf(w, bflo(uv.y), a2);
            a3 = fmaf(w, bfhi(uv.y), a3);
            a4 = fmaf(w, bflo(uv.z), a4);
            a5 = fmaf(w, bfhi(uv.z), a5);
            a6 = fmaf(w, bflo(uv.w), a6);
            a7 = fmaf(w, bfhi(uv.w), a7);

            s = sn; eb = ebn;
        }
    }

    ss += __shfl_xor(ss, 16);
    ss += __shfl_xor(ss, 32);
    a0 += __shfl_xor(a0, 16); a0 += __shfl_xor(a0, 32);
    a1 += __shfl_xor(a1, 16); a1 += __shfl_xor(a1, 32);
    a2 += __shfl_xor(a2, 16); a2 += __shfl_xor(a2, 32);
    a3 += __shfl_xor(a3, 16); a3 += __shfl_xor(a3, 32);
    a4 += __shfl_xor(a4, 16); a4 += __shfl_xor(a4, 32);
    a5 += __shfl_xor(a5, 16); a5 += __shfl_xor(a5, 32);
    a6 += __shfl_xor(a6, 16); a6 += __shfl_xor(a6, 32);
    a7 += __shfl_xor(a7, 16); a7 += __shfl_xor(a7, 32);

    if (g == 0) {
        const float inv = 1.f / fmaxf(ss, 1e-12f);
        uint4 o;
        o.x = (uint)f2bf(a0 * inv) | ((uint)f2bf(a1 * inv) << 16);
        o.y = (uint)f2bf(a2 * inv) | ((uint)f2bf(a3 * inv) << 16);
        o.z = (uint)f2bf(a4 * inv) | ((uint)f2bf(a5 * inv) << 16);
        o.w = (uint)f2bf(a6 * inv) | ((uint)f2bf(a7 * inv) << 16);
        *(uint4*)(aggb + (size_t)d * DIM + 8 * t) = o;
    }
}

// ----------------------------------------------------------------- launch
extern "C" void kernel_launch(void* const* d_in, const int* in_sizes, int n_in,
                              void* d_out, int out_size, void* d_ws, size_t ws_size,
                              hipStream_t stream)
{
    const float* x         = (const float*)d_in[0];
    const int*   edge_idx  = (const int*)d_in[1];   // [2,E]: row0=src, row1=dst
    const float* edge_attr = (const float*)d_in[2];
    const float* Wq        = (const float*)d_in[3];
    const float* Wk        = (const float*)d_in[4];
    const float* Wv        = (const float*)d_in[5];
    const float* We        = (const float*)d_in[6];
    const float* Wo        = (const float*)d_in[7];
    const float* bo        = (const float*)d_in[8];
    const float* Wm        = (const float*)d_in[9];
    const float* bm        = (const float*)d_in[10];
    float* out = (float*)d_out;

    const int* src = edge_idx;
    const int* dst = edge_idx + NE;

    // workspace layout
    ushort* xb   = (ushort*)d_ws;                       // NN*128 us
    ushort* Qb   = xb + (size_t)NN * DIM;               // NN*128 us
    ushort* KVb  = Qb + (size_t)NN * DIM;               // NN*256 us (K|V rows)
    ushort* aggb = KVb + (size_t)NN * 2 * DIM;          // NN*128 us
    uint*  ppack = (uint*)(aggb + (size_t)NN * DIM);    // NE uints
    uint2* pebp  = (uint2*)(ppack + NE);                // NE uint2 (bf16x4 eb)
    uint2* ebq   = pebp + NE;                           // NE uint2 (CSR order)
    ushort* srcp = (ushort*)(ebq + NE);                 // NE ushorts
    float* Wx    = (float*)(srcp + NE);                 // 16,384 f
    float* bprime= Wx + 16384;                          // 128 f
    short* BpQKV = (short*)(bprime + 128);              // 49,152 s
    short* BpOut = BpQKV + 49152;                       // 32,768 s
    int*   rowptr= (int*)(BpOut + 32768);               // 50,048 i (50001 used)
    int*   bkt_cnt    = rowptr + 50048;                 // 128 i
    int*   bkt_base   = bkt_cnt + 128;                  // 128 i (NBKT+1 used)
    int*   bkt_cursor = bkt_base + 128;                 // 128 i

    hipMemsetAsync(bkt_cnt, 0, 128 * sizeof(int), stream);

    prep_all_kernel<<<PREP_GRID, 256, 0, stream>>>(
        x, xb, dst, bkt_cnt, Wq, Wk, Wv, BpQKV, Wo, Wm, bo, bm, Wx, bprime);

    bkt_scan_kernel<<<1, 64, 0, stream>>>(bkt_cnt, bkt_base, bkt_cursor, rowptr);

    part_kernel<<<PART_GRID, 256, 0, stream>>>(
        src, dst, edge_attr, We, bkt_cursor, ppack, pebp, Wm, Wx, BpOut);

    csrqkv_kernel<<<CSRQ_GRID, 256, 0, stream>>>(
        bkt_base, ppack, pebp, rowptr, srcp, ebq, xb, BpQKV, Qb, KVb);

    attn_agg_kernel<<<NN / 4, 256, 0, stream>>>(Qb, KVb, rowptr, srcp,
                                                (const ushort*)ebq, aggb);

    out_mfma_kernel<<<GEMM_BLOCKS, 256, 0, stream>>>(xb, aggb, BpOut, bprime, out);
}

// Round 6
// 245.416 us; speedup vs baseline: 1.2184x; 1.0158x over previous
//
#include <hip/hip_runtime.h>
#include <hip/hip_bf16.h>
#include <math.h>

#define NN 50000
#define NE 800000
#define DIM 128
#define NH 4
#define HD 32
#define ATTN_SCALE 0.17677669529663687f   // 1/sqrt(32)
#define MTILE 64
#define GEMM_BLOCKS 782       // ceil(50000/64)
#define NBK 782               // fine buckets of 64 nodes: dst>>6
#define PTS 2048              // edges per partition block
#define HBLKS 104             // hist blocks: shallow atomic chains

// K1: hist + pack_qkv + Wx/b'
#define K1_QKV_BASE 104           // 192 blocks
#define K1_WXB_BASE 296           // 65 blocks (2 rows each, 130 rows)
#define K1_GRID     361
// K3: partition + pack_out + x->bf16
#define K3_PART_N     391         // ceil(NE/PTS)
#define K3_PACKO_BASE 391         // 128 blocks
#define K3_XCVT_BASE  519         // 6250 blocks
#define K3_GRID       6769
// K4: CSR (one block per fine bucket) + QKV GEMM
#define K4_CSR_N 782
#define K4_GRID  1564

typedef unsigned int uint;
typedef unsigned short ushort;
typedef __attribute__((ext_vector_type(8))) short short8;   // 8 bf16 (4 VGPRs)
typedef __attribute__((ext_vector_type(4))) float f32x4;    // MFMA acc

__device__ inline ushort f2bf(float f) {
    __hip_bfloat16 h = __float2bfloat16(f);   // round-to-nearest
    return *(ushort*)&h;
}
__device__ inline float bflo(uint u) { return __uint_as_float(u << 16); }
__device__ inline float bfhi(uint u) { return __uint_as_float(u & 0xffff0000u); }
__device__ inline float bf2f(ushort u) { return __uint_as_float((uint)u << 16); }

// ---------------------------------------------- K1: hist | pack_qkv | Wx,b'
// bkt_cnt pre-zeroed by memset. All three phases independent.
__global__ __launch_bounds__(256) void k1_kernel(
    const int* __restrict__ dst, int* __restrict__ bkt_cnt,
    const float* __restrict__ Wq, const float* __restrict__ Wk,
    const float* __restrict__ Wv, short* __restrict__ BpQKV,
    const float* __restrict__ Wo, const float* __restrict__ Wm,
    const float* __restrict__ bo, const float* __restrict__ bm,
    float* __restrict__ Wx, float* __restrict__ bprime)
{
    const int bid = blockIdx.x;
    const int tid = threadIdx.x;

    if (bid < HBLKS) {
        // fine-bucket histogram (grid-stride over edges)
        __shared__ int c[NBK];
        for (int l = tid; l < NBK; l += 256) c[l] = 0;
        __syncthreads();
        for (int e = bid * 256 + tid; e < NE; e += HBLKS * 256)
            atomicAdd(&c[dst[e] >> 6], 1);
        __syncthreads();
        for (int l = tid; l < NBK; l += 256)
            if (c[l]) atomicAdd(&bkt_cnt[l], c[l]);
    } else if (bid < K1_WXB_BASE) {
        // pack Wq/Wk/Wv into MFMA fragment order
        const int idx = (bid - K1_QKV_BASE) * 256 + tid;     // < 49152
        const int j = idx & 7, lane = (idx >> 3) & 63;
        const int rest = idx >> 9;                           // kc*24 + nt
        const int nt = rest % 24, kc = rest / 24;
        const int k = kc * 32 + (lane >> 4) * 8 + j;
        const int n = nt * 16 + (lane & 15);
        const float* W = (n < 128) ? Wq : (n < 256 ? Wk : Wv);
        BpQKV[idx] = (short)f2bf(W[k * 128 + (n & 127)]);
    } else {
        // Wx = Wo @ Wm2 (rows 128..255 of Wm); row 128 = b'
        const int r = (bid - K1_WXB_BASE) * 2 + (tid >> 7);
        const int j = tid & 127;
        if (r < 128) {
            float acc = 0.f;
            for (int t = 0; t < 128; ++t)
                acc = fmaf(Wo[r * 128 + t], Wm[(128 + t) * 128 + j], acc);
            Wx[r * 128 + j] = acc;
        } else if (r == 128) {
            float acc = bm[j];
            for (int t = 0; t < 128; ++t)
                acc = fmaf(bo[t], Wm[(128 + t) * 128 + j], acc);
            bprime[j] = acc;
        }
    }
}

// -------------------------------------- K2: parallel 782-bucket excl. scan
__global__ __launch_bounds__(256) void bkt_scan_kernel(
    const int* __restrict__ bkt_cnt,
    int* __restrict__ bkt_base, int* __restrict__ bkt_cursor,
    int* __restrict__ rowptr)
{
    __shared__ int part[256];
    const int tid = threadIdx.x;
    const int b0 = tid * 4;
    int v0 = 0, v1 = 0, v2 = 0, v3 = 0;
    if (b0 + 0 < NBK) v0 = bkt_cnt[b0 + 0];
    if (b0 + 1 < NBK) v1 = bkt_cnt[b0 + 1];
    if (b0 + 2 < NBK) v2 = bkt_cnt[b0 + 2];
    if (b0 + 3 < NBK) v3 = bkt_cnt[b0 + 3];
    const int s = v0 + v1 + v2 + v3;
    part[tid] = s;
    __syncthreads();
    for (int off = 1; off < 256; off <<= 1) {
        const int y = (tid >= off) ? part[tid - off] : 0;
        __syncthreads();
        part[tid] += y;
        __syncthreads();
    }
    const int ex = part[tid] - s;
    const int r0 = ex, r1 = ex + v0, r2 = ex + v0 + v1, r3 = ex + v0 + v1 + v2;
    if (b0 + 0 < NBK) { bkt_base[b0 + 0] = r0; bkt_cursor[b0 + 0] = r0; }
    if (b0 + 1 < NBK) { bkt_base[b0 + 1] = r1; bkt_cursor[b0 + 1] = r1; }
    if (b0 + 2 < NBK) { bkt_base[b0 + 2] = r2; bkt_cursor[b0 + 2] = r2; }
    if (b0 + 3 < NBK) { bkt_base[b0 + 3] = r3; bkt_cursor[b0 + 3] = r3; }
    if (tid == 255) bkt_base[NBK] = part[255];   // == NE
    if (tid == 0)   rowptr[NN] = NE;
}

// ------------------------------- K3: partition | pack_out | x->bf16 stream
__global__ __launch_bounds__(256) void k3_kernel(
    const int* __restrict__ src, const int* __restrict__ dst,
    const float* __restrict__ edge_attr, const float* __restrict__ We,
    int* __restrict__ bkt_cursor,
    uint* __restrict__ ppack, uint2* __restrict__ pebp,
    const float* __restrict__ Wm, const float* __restrict__ Wx,
    short* __restrict__ BpOut,
    const float* __restrict__ x, ushort* __restrict__ xb)
{
    const int bid = blockIdx.x;
    const int tid = threadIdx.x;

    if (bid < K3_PART_N) {
        __shared__ int cnt[NBK], rbase[NBK], cnt2[NBK];
        for (int l = tid; l < NBK; l += 256) cnt[l] = 0;
        __syncthreads();
        const int e0 = bid * PTS;
        #pragma unroll
        for (int it = 0; it < 8; ++it) {
            const int e = e0 + it * 256 + tid;
            if (e < NE) atomicAdd(&cnt[dst[e] >> 6], 1);
        }
        __syncthreads();
        for (int l = tid; l < NBK; l += 256) {
            const int c = cnt[l];
            rbase[l] = c ? atomicAdd(&bkt_cursor[l], c) : 0;
            cnt2[l] = 0;
        }
        __syncthreads();
        #pragma unroll
        for (int it = 0; it < 8; ++it) {
            const int e = e0 + it * 256 + tid;
            if (e < NE) {
                const int d = dst[e];
                const int b = d >> 6;
                const int r = atomicAdd(&cnt2[b], 1);
                const int pos = rbase[b] + r;
                ppack[pos] = (uint)src[e] | ((uint)(d & 63) << 16);
                const float a0 = edge_attr[e * 3 + 0];
                const float a1 = edge_attr[e * 3 + 1];
                const float a2 = edge_attr[e * 3 + 2];
                const float b0 = a0 * We[0] + a1 * We[4] + a2 * We[8];
                const float b1 = a0 * We[1] + a1 * We[5] + a2 * We[9];
                const float b2 = a0 * We[2] + a1 * We[6] + a2 * We[10];
                const float b3 = a0 * We[3] + a1 * We[7] + a2 * We[11];
                uint2 ep;
                ep.x = (uint)f2bf(b0) | ((uint)f2bf(b1) << 16);
                ep.y = (uint)f2bf(b2) | ((uint)f2bf(b3) << 16);
                pebp[pos] = ep;
            }
        }
    } else if (bid < K3_XCVT_BASE) {
        // pack epilogue B operand [Wm1; Wx]
        const int idx = (bid - K3_PACKO_BASE) * 256 + tid;   // < 32768
        const int j = idx & 7, lane = (idx >> 3) & 63;
        const int rest = idx >> 9;                           // kc*8 + nt
        const int nt = rest & 7, kc = rest >> 3;
        const int k = kc * 32 + (lane >> 4) * 8 + j;
        const int n = nt * 16 + (lane & 15);
        const float v = (k < 128) ? Wm[k * 128 + n] : Wx[(k - 128) * 128 + n];
        BpOut[idx] = (short)f2bf(v);
    } else {
        // x -> bf16 (one float4 per thread)
        const int i = (bid - K3_XCVT_BASE) * 256 + tid;      // < 1,600,000
        const float4 v = ((const float4*)x)[i];
        ushort4 o;
        o.x = f2bf(v.x); o.y = f2bf(v.y); o.z = f2bf(v.z); o.w = f2bf(v.w);
        ((ushort4*)xb)[i] = o;
    }
}

// ------------------------- K4: CSR scatter (1 block per fine bucket) | QKV
__global__ __launch_bounds__(256) void k4_kernel(
    const int* __restrict__ bkt_base,
    const uint* __restrict__ ppack, const uint2* __restrict__ pebp,
    int* __restrict__ rowptr,
    ushort* __restrict__ srcp, uint2* __restrict__ ebq,
    const ushort* __restrict__ xb, const short* __restrict__ BpQKV,
    ushort* __restrict__ Qb, ushort* __restrict__ KVb)
{
    const int bid = blockIdx.x;
    const int tid = threadIdx.x;

    if (bid < K4_CSR_N) {
        __shared__ int cnt[64];
        __shared__ int pre[64];
        const int base = bkt_base[bid];
        const int n = bkt_base[bid + 1] - base;
        const int node0 = bid << 6;

        if (tid < 64) cnt[tid] = 0;
        __syncthreads();
        for (int i = base + tid; i < base + n; i += 256)
            atomicAdd(&cnt[ppack[i] >> 16], 1);
        __syncthreads();

        if (tid < 64) {
            const int c = cnt[tid];
            int xsc = c;                      // inclusive scan over wave 0
            #pragma unroll
            for (int off = 1; off < 64; off <<= 1) {
                const int y = __shfl_up(xsc, off);
                if (tid >= off) xsc += y;
            }
            const int ex = base + xsc - c;    // exclusive
            pre[tid] = ex;
            const int g = node0 + tid;
            if (g < NN) rowptr[g] = ex;
        }
        __syncthreads();

        for (int i = base + tid; i < base + n; i += 256) {
            const uint v = ppack[i];
            const int pos = atomicAdd(&pre[v >> 16], 1);
            srcp[pos] = (ushort)(v & 0xFFFFu);
            ebq[pos] = pebp[i];
        }
    } else {
        // ---- QKV MFMA: Q -> Qb; K,V interleaved per node in KVb (512B rows)
        const int qb = bid - K4_CSR_N;
        const int wave = tid >> 6;
        const int lane = tid & 63;
        const int m = lane & 15, quad = lane >> 4;
        const int row0w = qb * MTILE + wave * 16;
        const int arow = row0w + m;
        const bool rowok = arow < NN;

        short8 a[4];
        #pragma unroll
        for (int kc = 0; kc < 4; ++kc)
            a[kc] = rowok ? *(const short8*)(xb + (size_t)arow * 128 + kc * 32 + quad * 8)
                          : (short8)(0);

        const int NT = 24;
        for (int nt = 0; nt < NT; nt += 2) {
            f32x4 acc0 = {0.f, 0.f, 0.f, 0.f}, acc1 = {0.f, 0.f, 0.f, 0.f};
            #pragma unroll
            for (int kc = 0; kc < 4; ++kc) {
                const short8 b0 = *(const short8*)(BpQKV + ((size_t)(kc * NT + nt) * 64 + lane) * 8);
                const short8 b1 = *(const short8*)(BpQKV + ((size_t)(kc * NT + nt + 1) * 64 + lane) * 8);
                acc0 = __builtin_amdgcn_mfma_f32_16x16x32_bf16(a[kc], b0, acc0, 0, 0, 0);
                acc1 = __builtin_amdgcn_mfma_f32_16x16x32_bf16(a[kc], b1, acc1, 0, 0, 0);
            }
            #pragma unroll
            for (int t = 0; t < 2; ++t) {
                const f32x4 acc = t ? acc1 : acc0;
                const int c = (nt + t) * 16 + m;           // global col in [0,384)
                #pragma unroll
                for (int g = 0; g < 4; ++g) {
                    const int r = row0w + quad * 4 + g;
                    if (r < NN) {
                        if (c < 128) Qb[(size_t)r * 128 + c] = f2bf(acc[g]);
                        else        KVb[(size_t)r * 256 + (c - 128)] = f2bf(acc[g]);
                    }
                }
            }
        }
    }
}

// ---------------------------------------------------------------- OUT MFMA
__global__ __launch_bounds__(256) void out_mfma_kernel(
    const ushort* __restrict__ xb, const ushort* __restrict__ aggb,
    const short* __restrict__ Bp, const float* __restrict__ bprime,
    float* __restrict__ out)
{
    const int wave = threadIdx.x >> 6;
    const int lane = threadIdx.x & 63;
    const int m = lane & 15, quad = lane >> 4;
    const int row0w = blockIdx.x * MTILE + wave * 16;
    const int arow = row0w + m;
    const bool rowok = arow < NN;

    short8 a[8];
    #pragma unroll
    for (int kc = 0; kc < 4; ++kc)
        a[kc] = rowok ? *(const short8*)(xb + (size_t)arow * 128 + kc * 32 + quad * 8)
                      : (short8)(0);
    #pragma unroll
    for (int kc = 0; kc < 4; ++kc)
        a[4 + kc] = rowok ? *(const short8*)(aggb + (size_t)arow * 128 + kc * 32 + quad * 8)
                          : (short8)(0);

    const int NT = 8;
    for (int nt = 0; nt < NT; nt += 2) {
        f32x4 acc0 = {0.f, 0.f, 0.f, 0.f}, acc1 = {0.f, 0.f, 0.f, 0.f};
        #pragma unroll
        for (int kc = 0; kc < 8; ++kc) {
            const short8 b0 = *(const short8*)(Bp + ((size_t)(kc * NT + nt) * 64 + lane) * 8);
            const short8 b1 = *(const short8*)(Bp + ((size_t)(kc * NT + nt + 1) * 64 + lane) * 8);
            acc0 = __builtin_amdgcn_mfma_f32_16x16x32_bf16(a[kc], b0, acc0, 0, 0, 0);
            acc1 = __builtin_amdgcn_mfma_f32_16x16x32_bf16(a[kc], b1, acc1, 0, 0, 0);
        }
        #pragma unroll
        for (int t = 0; t < 2; ++t) {
            const f32x4 acc = t ? acc1 : acc0;
            const int c = (nt + t) * 16 + m;           // global col in [0,128)
            const float bb = bprime[c];
            #pragma unroll
            for (int g = 0; g < 4; ++g) {
                const int r = row0w + quad * 4 + g;
                if (r < NN) out[(size_t)r * 128 + c] = fmaxf(acc[g] + bb, 0.f);
            }
        }
    }
}

// ----------------------------------------- FUSED attn + softmax + aggregate
// One wave per node; 4 groups of 16 lanes, each group owns one edge.
// K|V interleaved (512B/node): one base address, adjacent segments.
// (Structure pinned at the random-gather service floor — do not restructure.)
__global__ __launch_bounds__(256) void attn_agg_kernel(
    const ushort* __restrict__ Qb, const ushort* __restrict__ KVb,
    const int* __restrict__ rowptr, const ushort* __restrict__ srcp,
    const ushort* __restrict__ ebb, ushort* __restrict__ aggb)
{
    const int tid = threadIdx.x;
    const int d = blockIdx.x * 4 + (tid >> 6);
    const int lane = tid & 63;
    const int g = lane >> 4;          // edge slot within quad
    const int t = lane & 15;          // 8-dim chunk index
    const int h = t >> 2;             // head of this chunk
    const int begin = rowptr[d];
    const int end   = rowptr[d + 1];

    const uint4 uq = *(const uint4*)(Qb + (size_t)d * DIM + 8 * t);
    const float q0 = bflo(uq.x), q1 = bfhi(uq.x);
    const float q2 = bflo(uq.y), q3 = bfhi(uq.y);
    const float q4 = bflo(uq.z), q5 = bfhi(uq.z);
    const float q6 = bflo(uq.w), q7 = bfhi(uq.w);

    float ss = 0.f;
    float a0 = 0.f, a1 = 0.f, a2 = 0.f, a3 = 0.f;
    float a4 = 0.f, a5 = 0.f, a6 = 0.f, a7 = 0.f;

    if (begin < end) {
        int ec = begin + g;
        if (ec >= end) ec = end - 1;
        int s    = (int)srcp[ec];
        float eb = bf2f(ebb[ec * 4 + h]);

        for (int p = begin; p < end; p += 4) {
            const bool ok = (p + g) < end;
            const int pn = p + 4;
            int sn = s; float ebn = eb;
            if (pn < end) {
                int en = pn + g;
                if (en >= end) en = end - 1;
                sn  = (int)srcp[en];
                ebn = bf2f(ebb[en * 4 + h]);
            }

            const ushort* kv = KVb + (size_t)s * 256 + 8 * t;
            const uint4 uk = *(const uint4*)(kv);
            const uint4 uv = *(const uint4*)(kv + 128);

            float da = q0 * bflo(uk.x);
            float db = q1 * bfhi(uk.x);
            da = fmaf(q2, bflo(uk.y), da);
            db = fmaf(q3, bfhi(uk.y), db);
            da = fmaf(q4, bflo(uk.z), da);
            db = fmaf(q5, bfhi(uk.z), db);
            da = fmaf(q6, bflo(uk.w), da);
            db = fmaf(q7, bfhi(uk.w), db);
            float part = da + db;
            part += __shfl_xor(part, 1);
            part += __shfl_xor(part, 2);

            float a = fmaf(part, ATTN_SCALE, eb);
            a = (a >= 0.f) ? a : 0.2f * a;
            float w = ok ? __expf(a) : 0.f;

            ss += w;
            a0 = fmaf(w, bflo(uv.x), a0);
            a1 = fmaf(w, bfhi(uv.x), a1);
            a2 = fmaf(w, bflo(uv.y), a2);
            a3 = fmaf(w, bfhi(uv.y), a3);
            a4 = fmaf(w, bflo(uv.z), a4);
            a5 = fmaf(w, bfhi(uv.z), a5);
            a6 = fmaf(w, bflo(uv.w), a6);
            a7 = fmaf(w, bfhi(uv.w), a7);

            s = sn; eb = ebn;
        }
    }

    ss += __shfl_xor(ss, 16);
    ss += __shfl_xor(ss, 32);
    a0 += __shfl_xor(a0, 16); a0 += __shfl_xor(a0, 32);
    a1 += __shfl_xor(a1, 16); a1 += __shfl_xor(a1, 32);
    a2 += __shfl_xor(a2, 16); a2 += __shfl_xor(a2, 32);
    a3 += __shfl_xor(a3, 16); a3 += __shfl_xor(a3, 32);
    a4 += __shfl_xor(a4, 16); a4 += __shfl_xor(a4, 32);
    a5 += __shfl_xor(a5, 16); a5 += __shfl_xor(a5, 32);
    a6 += __shfl_xor(a6, 16); a6 += __shfl_xor(a6, 32);
    a7 += __shfl_xor(a7, 16); a7 += __shfl_xor(a7, 32);

    if (g == 0) {
        const float inv = 1.f / fmaxf(ss, 1e-12f);
        uint4 o;
        o.x = (uint)f2bf(a0 * inv) | ((uint)f2bf(a1 * inv) << 16);
        o.y = (uint)f2bf(a2 * inv) | ((uint)f2bf(a3 * inv) << 16);
        o.z = (uint)f2bf(a4 * inv) | ((uint)f2bf(a5 * inv) << 16);
        o.w = (uint)f2bf(a6 * inv) | ((uint)f2bf(a7 * inv) << 16);
        *(uint4*)(aggb + (size_t)d * DIM + 8 * t) = o;
    }
}

// ----------------------------------------------------------------- launch
extern "C" void kernel_launch(void* const* d_in, const int* in_sizes, int n_in,
                              void* d_out, int out_size, void* d_ws, size_t ws_size,
                              hipStream_t stream)
{
    const float* x         = (const float*)d_in[0];
    const int*   edge_idx  = (const int*)d_in[1];   // [2,E]: row0=src, row1=dst
    const float* edge_attr = (const float*)d_in[2];
    const float* Wq        = (const float*)d_in[3];
    const float* Wk        = (const float*)d_in[4];
    const float* Wv        = (const float*)d_in[5];
    const float* We        = (const float*)d_in[6];
    const float* Wo        = (const float*)d_in[7];
    const float* bo        = (const float*)d_in[8];
    const float* Wm        = (const float*)d_in[9];
    const float* bm        = (const float*)d_in[10];
    float* out = (float*)d_out;

    const int* src = edge_idx;
    const int* dst = edge_idx + NE;

    // workspace layout
    ushort* xb   = (ushort*)d_ws;                       // NN*128 us
    ushort* Qb   = xb + (size_t)NN * DIM;               // NN*128 us
    ushort* KVb  = Qb + (size_t)NN * DIM;               // NN*256 us (K|V rows)
    ushort* aggb = KVb + (size_t)NN * 2 * DIM;          // NN*128 us
    uint*  ppack = (uint*)(aggb + (size_t)NN * DIM);    // NE uints
    uint2* pebp  = (uint2*)(ppack + NE);                // NE uint2 (bf16x4 eb)
    uint2* ebq   = pebp + NE;                           // NE uint2 (CSR order)
    ushort* srcp = (ushort*)(ebq + NE);                 // NE ushorts
    float* Wx    = (float*)(srcp + NE);                 // 16,384 f
    float* bprime= Wx + 16384;                          // 128 f
    short* BpQKV = (short*)(bprime + 128);              // 49,152 s
    short* BpOut = BpQKV + 49152;                       // 32,768 s
    int*   rowptr= (int*)(BpOut + 32768);               // 50,048 i (50001 used)
    int*   bkt_cnt    = rowptr + 50048;                 // 800 i (782 used)
    int*   bkt_base   = bkt_cnt + 800;                  // 800 i (783 used)
    int*   bkt_cursor = bkt_base + 800;                 // 800 i (782 used)

    hipMemsetAsync(bkt_cnt, 0, NBK * sizeof(int), stream);

    k1_kernel<<<K1_GRID, 256, 0, stream>>>(
        dst, bkt_cnt, Wq, Wk, Wv, BpQKV, Wo, Wm, bo, bm, Wx, bprime);

    bkt_scan_kernel<<<1, 256, 0, stream>>>(bkt_cnt, bkt_base, bkt_cursor, rowptr);

    k3_kernel<<<K3_GRID, 256, 0, stream>>>(
        src, dst, edge_attr, We, bkt_cursor, ppack, pebp, Wm, Wx, BpOut, x, xb);

    k4_kernel<<<K4_GRID, 256, 0, stream>>>(
        bkt_base, ppack, pebp, rowptr, srcp, ebq, xb, BpQKV, Qb, KVb);

    attn_agg_kernel<<<NN / 4, 256, 0, stream>>>(Qb, KVb, rowptr, srcp,
                                                (const ushort*)ebq, aggb);

    out_mfma_kernel<<<GEMM_BLOCKS, 256, 0, stream>>>(xb, aggb, BpOut, bprime, out);
}